// Round 2
// baseline (7924.872 us; speedup 1.0000x reference)
//
#include <hip/hip_runtime.h>
#include <hip/hip_bf16.h>

#define Bsz 4
#define Tt 2048
#define Ll 4096

// ---------------------------------------------------------------------------
// Compose upsample-conv weights with fuse matmul:
// A[o,i,tap] = sum_c fus_w[o,c] * up_w[i,c,ktap]
// even taps (x[t-1],x[t],x[t+1]) use up_w k={4,2,0}; odd (x[t],x[t+1]) k={3,1}
// Also: FWS[s][o] = fus_w[o,256+s]; BIAS2[o] = fus_b[o] + sum_c fus_w[o,c]*up_b[c]
// ---------------------------------------------------------------------------
__global__ void k_compose(const float* __restrict__ up_w, const float* __restrict__ fus_w,
                          const float* __restrict__ fus_b, const float* __restrict__ up_b,
                          float* __restrict__ AE, float* __restrict__ AO,
                          float* __restrict__ FWS, float* __restrict__ BIAS2){
  int i = blockIdx.x;     // 0..255
  int o = threadIdx.x;    // 0..127
  float a0=0.f,a1=0.f,a2=0.f,a3=0.f,a4=0.f;
  for (int c=0;c<256;c++){
    float f = fus_w[o*384+c];
    const float* w = up_w + ((size_t)i*256+c)*5;
    a0 += f*w[0]; a1 += f*w[1]; a2 += f*w[2];
    a3 += f*w[3]; a4 += f*w[4];
  }
  AE[(i*3+0)*128+o]=a4; AE[(i*3+1)*128+o]=a2; AE[(i*3+2)*128+o]=a0;
  AO[(i*2+0)*128+o]=a3; AO[(i*2+1)*128+o]=a1;
  if (i<128) FWS[i*128+o] = fus_w[o*384+256+i];
  if (i==0){
    float bb = fus_b[o];
    for (int c=0;c<256;c++) bb += fus_w[o*384+c]*up_b[c];
    BIAS2[o]=bb;
  }
}

// ---------------------------------------------------------------------------
// Fused upsample+fuse matmul. Block = (b, 4 t-values) x 128 o-threads.
// h0[b,l,o] layout (B,L,128). Also accumulates groupnorm sum/sumsq per batch.
// ---------------------------------------------------------------------------
__global__ __launch_bounds__(128) void k_fuse(const float* __restrict__ x, const float* __restrict__ skip,
                       const float* __restrict__ AE, const float* __restrict__ AO,
                       const float* __restrict__ FWS, const float* __restrict__ BIAS2,
                       float* __restrict__ h0, float* __restrict__ gst){
  int b = blockIdx.y;
  int t0 = blockIdx.x*4;
  int o = threadIdx.x;
  float bias = BIAS2[o];
  float acc[8];
  #pragma unroll
  for (int q=0;q<8;q++) acc[q]=bias;

  for (int i=0;i<256;i++){
    float xv[6];
    const float* xp = x + ((size_t)b*256+i)*Tt;
    #pragma unroll
    for (int j=0;j<6;j++){
      int t = t0-1+j;
      xv[j] = (t>=0 && t<Tt) ? xp[t] : 0.f;
    }
    float ae0 = AE[(i*3+0)*128+o], ae1 = AE[(i*3+1)*128+o], ae2 = AE[(i*3+2)*128+o];
    float ao0 = AO[(i*2+0)*128+o], ao1 = AO[(i*2+1)*128+o];
    #pragma unroll
    for (int tt=0;tt<4;tt++){
      acc[2*tt]   += xv[tt]*ae0 + xv[tt+1]*ae1 + xv[tt+2]*ae2;
      acc[2*tt+1] += xv[tt+1]*ao0 + xv[tt+2]*ao1;
    }
  }
  // skip contribution
  for (int s=0;s<128;s++){
    float f = FWS[s*128+o];
    const float* sp = skip + ((size_t)b*128+s)*Ll + 2*t0;
    #pragma unroll
    for (int q=0;q<8;q++) acc[q] += f*sp[q];
  }
  float s1=0.f, s2=0.f;
  #pragma unroll
  for (int q=0;q<8;q++){
    int l = 2*t0+q;
    h0[((size_t)b*Ll + l)*128 + o] = acc[q];
    s1 += acc[q]; s2 += acc[q]*acc[q];
  }
  __shared__ float red0[128], red1[128];
  red0[o]=s1; red1[o]=s2;
  __syncthreads();
  for (int st=64; st>0; st>>=1){
    if (o<st){ red0[o]+=red0[o+st]; red1[o]+=red1[o+st]; }
    __syncthreads();
  }
  if (o==0){ atomicAdd(&gst[b*2], red0[0]); atomicAdd(&gst[b*2+1], red1[0]); }
}

__global__ void k_gnfin(float* gst){
  int b = threadIdx.x;
  if (b < Bsz){
    float n = (float)Ll*128.f;
    float mu = gst[b*2]/n;
    float var = gst[b*2+1]/n - mu*mu;
    gst[8+b]=mu; gst[12+b]=rsqrtf(var+1e-5f);
  }
}

__global__ void k_gnapply(const float* __restrict__ h0, const float* __restrict__ gn_w,
                          const float* __restrict__ gn_b, const float* __restrict__ pa,
                          const float* __restrict__ gst, float* __restrict__ hres){
  size_t idx = (size_t)blockIdx.x*256 + threadIdx.x;
  int c = (int)(idx & 127);
  int b = (int)(idx >> 19);   // L*128 = 2^19
  float mu = gst[8+b], inv = gst[12+b];
  float a = pa[0];
  float v = (h0[idx]-mu)*inv*gn_w[c] + gn_b[c];
  hres[idx] = v>=0.f ? v : a*v;
}

// LayerNorm over 128 channels; 4 rows per block, one wave (64 lanes) per row
__global__ __launch_bounds__(256) void k_ln(const float* __restrict__ hres, const float* __restrict__ lnw,
                     const float* __restrict__ lnb, float* __restrict__ xn){
  int row = blockIdx.x*4 + (threadIdx.x>>6);
  int lane = threadIdx.x & 63;
  const float* hp = hres + (size_t)row*128;
  float v0 = hp[lane], v1 = hp[lane+64];
  float s = v0+v1, q = v0*v0+v1*v1;
  #pragma unroll
  for (int off=32; off>0; off>>=1){
    s += __shfl_xor(s, off, 64);
    q += __shfl_xor(q, off, 64);
  }
  float mu = s*(1.f/128.f);
  float rs = rsqrtf(q*(1.f/128.f)-mu*mu + 1e-5f);
  float* xp = xn + (size_t)row*128;
  xp[lane]    = (v0-mu)*rs*lnw[lane]    + lnb[lane];
  xp[lane+64] = (v1-mu)*rs*lnw[lane+64] + lnb[lane+64];
}

// ---------------------------------------------------------------------------
// GEMM in_proj: xz[row, 0:512] = xn[amap(row), 0:128] @ W^T   (W: 512x128)
// rev flips the l index when READING xn.
// ---------------------------------------------------------------------------
__global__ __launch_bounds__(256) void k_gemm_in(const float* __restrict__ Asrc, const float* __restrict__ W,
                          float* __restrict__ C, int rev){
  const int K = 128, N = 512;
  __shared__ float As[16][68];
  __shared__ float Ws[16][68];
  int row0 = blockIdx.x*64;
  int n0 = blockIdx.y*64;
  int tid = threadIdx.x;
  int tx = tid & 15, ty = tid >> 4;
  float acc[4][4] = {};
  int lk = tid & 15;
  int lm = tid >> 4;
  for (int kb=0; kb<K; kb+=16){
    #pragma unroll
    for (int j=0;j<4;j++){
      int m = lm + 16*j;
      int r = row0 + m;
      int p = r & (Ll-1); int b = r >> 12;
      int src = (b<<12) + (rev ? (Ll-1-p) : p);
      As[lk][m] = Asrc[(size_t)src*K + kb + lk];
      Ws[lk][m] = W[(size_t)(n0+m)*K + kb + lk];
    }
    __syncthreads();
    #pragma unroll
    for (int k=0;k<16;k++){
      float4 av = *(const float4*)&As[k][ty*4];
      float4 bv = *(const float4*)&Ws[k][tx*4];
      float a[4] = {av.x,av.y,av.z,av.w};
      float bb[4] = {bv.x,bv.y,bv.z,bv.w};
      #pragma unroll
      for (int i2=0;i2<4;i2++)
        #pragma unroll
        for (int j2=0;j2<4;j2++)
          acc[i2][j2] += a[i2]*bb[j2];
    }
    __syncthreads();
  }
  #pragma unroll
  for (int i2=0;i2<4;i2++){
    float* cp = C + (size_t)(row0+ty*4+i2)*N + n0 + tx*4;
    cp[0]=acc[i2][0]; cp[1]=acc[i2][1]; cp[2]=acc[i2][2]; cp[3]=acc[i2][3];
  }
}

// Depthwise causal conv (K=4) + bias + SiLU.  xz rows of 512, first 256 = xi_raw.
__global__ void k_conv(const float* __restrict__ xz, const float* __restrict__ cw,
                       const float* __restrict__ cb, float* __restrict__ xi){
  size_t idx = (size_t)blockIdx.x*256 + threadIdx.x;  // over B*L*256
  int d = (int)(idx & 255);
  size_t row = idx >> 8;     // b*L + p
  int p = (int)(row & (Ll-1));
  float wv[4];
  #pragma unroll
  for (int k=0;k<4;k++) wv[k] = cw[d*4+k];
  float acc = cb[d];
  #pragma unroll
  for (int k=0;k<4;k++){
    int q = p-3+k;
    if (q>=0){
      long long qrow = (long long)row - 3 + k;
      acc += wv[k]*xz[qrow*512 + d];
    }
  }
  xi[idx] = acc/(1.f+__expf(-acc));
}

// x_proj: dbl[row, 0:40] = xi[row,0:256] @ xw^T   (xw: 40x256). 8 rows/block.
__global__ __launch_bounds__(320) void k_xproj(const float* __restrict__ xi, const float* __restrict__ xw,
                        float* __restrict__ dbl){
  __shared__ float xs[8][256];
  int tid = threadIdx.x;
  size_t row0 = (size_t)blockIdx.x*8;
  for (int idx=tid; idx<2048; idx+=320) xs[idx>>8][idx&255] = xi[row0*256 + idx];
  __syncthreads();
  int rloc = tid/40, r = tid%40;
  if (rloc<8){
    float acc=0.f;
    for (int d2=0;d2<256;d2++) acc += xs[rloc][d2]*xw[r*256+d2];
    dbl[(row0+rloc)*40 + r] = acc;
  }
}

// dt_proj + softplus: dt[row,d] = softplus(sum_r dbl[row,r]*dtw[d,r] + dtb[d])
__global__ void k_dt(const float* __restrict__ dbl, const float* __restrict__ dtw,
                     const float* __restrict__ dtb, float* __restrict__ dt){
  int row = blockIdx.x; int d = threadIdx.x;
  const float* dp = dbl + (size_t)row*40;
  float acc = dtb[d];
  #pragma unroll
  for (int r=0;r<8;r++) acc += dp[r]*dtw[d*8+r];
  float v = (acc>20.f)? acc : log1pf(__expf(acc));
  dt[(size_t)row*256 + d] = v;
}

// Selective scan. Block = 16 d-groups x 16 n; grid (16, B). Sequential over L.
__global__ __launch_bounds__(256) void k_scan(const float* __restrict__ dt, const float* __restrict__ dbl,
                      const float* __restrict__ xi, const float* __restrict__ Alog,
                      const float* __restrict__ Dpw, float* __restrict__ y){
  int b = blockIdx.y;
  int dg = threadIdx.x >> 4;
  int n  = threadIdx.x & 15;
  int d = blockIdx.x*16 + dg;
  float A = -__expf(Alog[d*16+n]);
  float Dp = Dpw[d];
  float h = 0.f;
  const float* dtp = dt + (size_t)b*Ll*256 + d;
  const float* xip = xi + (size_t)b*Ll*256 + d;
  const float* blp = dbl + (size_t)b*Ll*40;
  float* yp = y + (size_t)b*Ll*256 + d;
  #pragma unroll 4
  for (int p=0;p<Ll;p++){
    float dtv = dtp[(size_t)p*256];
    float xiv = xip[(size_t)p*256];
    float Bc = blp[p*40 + 8 + n];
    float Cc = blp[p*40 + 24 + n];
    float dA = __expf(dtv*A);
    h = dA*h + dtv*Bc*xiv;
    float contrib = h*Cc;
    #pragma unroll
    for (int off=8; off>0; off>>=1) contrib += __shfl_xor(contrib, off, 16);
    if (n==0) yp[(size_t)p*256] = contrib + Dp*xiv;
  }
}

// gate: y *= silu(z), z = xz[row, 256+d]
__global__ void k_gate(float* __restrict__ y, const float* __restrict__ xz){
  size_t idx = (size_t)blockIdx.x*256 + threadIdx.x;
  int d = (int)(idx & 255); size_t row = idx >> 8;
  float z = xz[row*512 + 256 + d];
  y[idx] *= z/(1.f+__expf(-z));
}

// GEMM out_proj with rev on STORE, accumulating into hres.
__global__ __launch_bounds__(256) void k_gemm_out(const float* __restrict__ Asrc, const float* __restrict__ W,
                           float* __restrict__ C, int rev){
  const int K=256, N=128;
  __shared__ float As[16][68];
  __shared__ float Ws[16][68];
  int row0 = blockIdx.x*64, n0 = blockIdx.y*64;
  int tid=threadIdx.x, tx=tid&15, ty=tid>>4;
  float acc[4][4]={};
  int lk=tid&15, lm=tid>>4;
  for (int kb=0;kb<K;kb+=16){
    #pragma unroll
    for (int j=0;j<4;j++){
      int m=lm+16*j;
      As[lk][m] = Asrc[(size_t)(row0+m)*K + kb+lk];
      Ws[lk][m] = W[(size_t)(n0+m)*K + kb+lk];
    }
    __syncthreads();
    #pragma unroll
    for (int k=0;k<16;k++){
      float4 av=*(const float4*)&As[k][ty*4];
      float4 bv=*(const float4*)&Ws[k][tx*4];
      float a[4]={av.x,av.y,av.z,av.w}, bb[4]={bv.x,bv.y,bv.z,bv.w};
      #pragma unroll
      for (int i2=0;i2<4;i2++)
        #pragma unroll
        for (int j2=0;j2<4;j2++)
          acc[i2][j2]+=a[i2]*bb[j2];
    }
    __syncthreads();
  }
  #pragma unroll
  for (int i2=0;i2<4;i2++){
    int r = row0+ty*4+i2;
    int p = r & (Ll-1), b = r >> 12;
    int dstrow = (b<<12) + (rev ? (Ll-1-p) : p);
    float* cp = C + (size_t)dstrow*N + n0 + tx*4;
    #pragma unroll
    for (int j2=0;j2<4;j2++) cp[j2] += acc[i2][j2];
  }
}

// final transpose (B,L,128) fp32 -> (B,128,L) fp32
__global__ __launch_bounds__(256) void k_final(const float* __restrict__ hres, float* __restrict__ out){
  __shared__ float tile[64*129];
  int b = blockIdx.y, l0 = blockIdx.x*64;
  int tid = threadIdx.x;
  for (int q=0;q<32;q++){
    int idx = q*256 + tid;
    int l = idx >> 7, c = idx & 127;
    tile[l*129 + c] = hres[((size_t)b*Ll + l0 + l)*128 + c];
  }
  __syncthreads();
  int lo = tid & 63; int cbase = tid >> 6;
  for (int q=0;q<32;q++){
    int c = cbase + q*4;
    out[((size_t)b*128 + c)*Ll + l0 + lo] = tile[lo*129 + c];
  }
}

extern "C" void kernel_launch(void* const* d_in, const int* in_sizes, int n_in,
                              void* d_out, int out_size, void* d_ws, size_t ws_size,
                              hipStream_t stream){
  const float* x      = (const float*)d_in[0];
  const float* skip   = (const float*)d_in[1];
  const float* up_w   = (const float*)d_in[2];
  const float* up_b   = (const float*)d_in[3];
  const float* fus_w  = (const float*)d_in[4];
  const float* fus_b  = (const float*)d_in[5];
  const float* gn_w   = (const float*)d_in[6];
  const float* gn_b   = (const float*)d_in[7];
  const float* pa     = (const float*)d_in[8];
  const float* ln_w   = (const float*)d_in[9];
  const float* ln_b   = (const float*)d_in[10];
  const float* in_w   = (const float*)d_in[11];
  const float* conv_w = (const float*)d_in[12];
  const float* conv_b = (const float*)d_in[13];
  const float* xproj_w= (const float*)d_in[14];
  const float* dtproj_w=(const float*)d_in[15];
  const float* dtproj_b=(const float*)d_in[16];
  const float* A_log  = (const float*)d_in[17];
  const float* Dp     = (const float*)d_in[18];
  const float* out_w  = (const float*)d_in[19];

  float* w = (float*)d_ws;
  size_t off=0;
  float* AE = w+off; off += 256*3*128;
  float* AO = w+off; off += 256*2*128;
  float* FWS= w+off; off += 128*128;
  float* B2 = w+off; off += 128;
  float* GST= w+off; off += 16;
  float* H0 = w+off; off += (size_t)Bsz*Ll*128;
  float* HR = w+off; off += (size_t)Bsz*Ll*128;
  float* XN = w+off; off += (size_t)Bsz*Ll*128;
  float* XZ = w+off; off += (size_t)Bsz*Ll*512;
  float* XI = w+off; off += (size_t)Bsz*Ll*256;
  float* DBL= w+off; off += (size_t)Bsz*Ll*40;
  float* DTT= w+off; off += (size_t)Bsz*Ll*256;
  float* Y  = w+off; off += (size_t)Bsz*Ll*256;

  hipMemsetAsync(GST, 0, 16*sizeof(float), stream);
  k_compose<<<256,128,0,stream>>>(up_w, fus_w, fus_b, up_b, AE, AO, FWS, B2);
  k_fuse<<<dim3(Tt/4,Bsz),128,0,stream>>>(x, skip, AE, AO, FWS, B2, H0, GST);
  k_gnfin<<<1,64,0,stream>>>(GST);
  k_gnapply<<<8192,256,0,stream>>>(H0, gn_w, gn_b, pa, GST, HR);
  for (int i=0;i<2;i++){
    k_ln<<<Bsz*Ll/4,256,0,stream>>>(HR, ln_w + i*128, ln_b + i*128, XN);
    for (int dir=0;dir<2;dir++){
      int br = i*2+dir;
      k_gemm_in<<<dim3(256,8),256,0,stream>>>(XN, in_w + (size_t)br*512*128, XZ, dir);
      k_conv<<<Bsz*Ll,256,0,stream>>>(XZ, conv_w + br*256*4, conv_b + br*256, XI);
      k_xproj<<<Bsz*Ll/8,320,0,stream>>>(XI, xproj_w + br*40*256, DBL);
      k_dt<<<Bsz*Ll,256,0,stream>>>(DBL, dtproj_w + br*256*8, dtproj_b + br*256, DTT);
      k_scan<<<dim3(16,Bsz),256,0,stream>>>(DTT, DBL, XI, A_log + br*256*16, Dp + br*256, Y);
      k_gate<<<Bsz*Ll,256,0,stream>>>(Y, XZ);
      k_gemm_out<<<dim3(256,2),256,0,stream>>>(Y, out_w + (size_t)br*128*256, HR, dir);
    }
  }
  k_final<<<dim3(Ll/64,Bsz),256,0,stream>>>(HR, (float*)d_out);
}

// Round 3
// 1530.374 us; speedup vs baseline: 5.1784x; 5.1784x over previous
//
#include <hip/hip_runtime.h>
#include <hip/hip_bf16.h>

#define Bsz 4
#define Tt 2048
#define Ll 4096
#define NC 64      // chunks for scan
#define CH 64      // steps per chunk (NC*CH == Ll)

// ---------------------------------------------------------------------------
// Compose upsample-conv weights with fuse matmul:
// A[o,i,tap] = sum_c fus_w[o,c] * up_w[i,c,ktap]
// even taps (x[t-1],x[t],x[t+1]) use up_w k={4,2,0}; odd (x[t],x[t+1]) k={3,1}
// ---------------------------------------------------------------------------
__global__ void k_compose(const float* __restrict__ up_w, const float* __restrict__ fus_w,
                          const float* __restrict__ fus_b, const float* __restrict__ up_b,
                          float* __restrict__ AE, float* __restrict__ AO,
                          float* __restrict__ FWS, float* __restrict__ BIAS2){
  int i = blockIdx.x;     // 0..255
  int o = threadIdx.x;    // 0..127
  float a0=0.f,a1=0.f,a2=0.f,a3=0.f,a4=0.f;
  for (int c=0;c<256;c++){
    float f = fus_w[o*384+c];
    const float* w = up_w + ((size_t)i*256+c)*5;
    a0 += f*w[0]; a1 += f*w[1]; a2 += f*w[2];
    a3 += f*w[3]; a4 += f*w[4];
  }
  AE[(i*3+0)*128+o]=a4; AE[(i*3+1)*128+o]=a2; AE[(i*3+2)*128+o]=a0;
  AO[(i*2+0)*128+o]=a3; AO[(i*2+1)*128+o]=a1;
  if (i<128) FWS[i*128+o] = fus_w[o*384+256+i];
  if (i==0){
    float bb = fus_b[o];
    for (int c=0;c<256;c++) bb += fus_w[o*384+c]*up_b[c];
    BIAS2[o]=bb;
  }
}

// ---------------------------------------------------------------------------
// Fused upsample+fuse matmul. Block = (b, 4 t-values) x 128 o-threads.
// ---------------------------------------------------------------------------
__global__ __launch_bounds__(128) void k_fuse(const float* __restrict__ x, const float* __restrict__ skip,
                       const float* __restrict__ AE, const float* __restrict__ AO,
                       const float* __restrict__ FWS, const float* __restrict__ BIAS2,
                       float* __restrict__ h0, float* __restrict__ gst){
  int b = blockIdx.y;
  int t0 = blockIdx.x*4;
  int o = threadIdx.x;
  float bias = BIAS2[o];
  float acc[8];
  #pragma unroll
  for (int q=0;q<8;q++) acc[q]=bias;

  for (int i=0;i<256;i++){
    float xv[6];
    const float* xp = x + ((size_t)b*256+i)*Tt;
    #pragma unroll
    for (int j=0;j<6;j++){
      int t = t0-1+j;
      xv[j] = (t>=0 && t<Tt) ? xp[t] : 0.f;
    }
    float ae0 = AE[(i*3+0)*128+o], ae1 = AE[(i*3+1)*128+o], ae2 = AE[(i*3+2)*128+o];
    float ao0 = AO[(i*2+0)*128+o], ao1 = AO[(i*2+1)*128+o];
    #pragma unroll
    for (int tt=0;tt<4;tt++){
      acc[2*tt]   += xv[tt]*ae0 + xv[tt+1]*ae1 + xv[tt+2]*ae2;
      acc[2*tt+1] += xv[tt+1]*ao0 + xv[tt+2]*ao1;
    }
  }
  for (int s=0;s<128;s++){
    float f = FWS[s*128+o];
    const float* sp = skip + ((size_t)b*128+s)*Ll + 2*t0;
    #pragma unroll
    for (int q=0;q<8;q++) acc[q] += f*sp[q];
  }
  float s1=0.f, s2=0.f;
  #pragma unroll
  for (int q=0;q<8;q++){
    int l = 2*t0+q;
    h0[((size_t)b*Ll + l)*128 + o] = acc[q];
    s1 += acc[q]; s2 += acc[q]*acc[q];
  }
  __shared__ float red0[128], red1[128];
  red0[o]=s1; red1[o]=s2;
  __syncthreads();
  for (int st=64; st>0; st>>=1){
    if (o<st){ red0[o]+=red0[o+st]; red1[o]+=red1[o+st]; }
    __syncthreads();
  }
  if (o==0){ atomicAdd(&gst[b*2], red0[0]); atomicAdd(&gst[b*2+1], red1[0]); }
}

__global__ void k_gnfin(float* gst){
  int b = threadIdx.x;
  if (b < Bsz){
    float n = (float)Ll*128.f;
    float mu = gst[b*2]/n;
    float var = gst[b*2+1]/n - mu*mu;
    gst[8+b]=mu; gst[12+b]=rsqrtf(var+1e-5f);
  }
}

__global__ void k_gnapply(const float* __restrict__ h0, const float* __restrict__ gn_w,
                          const float* __restrict__ gn_b, const float* __restrict__ pa,
                          const float* __restrict__ gst, float* __restrict__ hres){
  size_t idx = (size_t)blockIdx.x*256 + threadIdx.x;
  int c = (int)(idx & 127);
  int b = (int)(idx >> 19);   // L*128 = 2^19
  float mu = gst[8+b], inv = gst[12+b];
  float a = pa[0];
  float v = (h0[idx]-mu)*inv*gn_w[c] + gn_b[c];
  hres[idx] = v>=0.f ? v : a*v;
}

// LayerNorm over 128 channels; 4 rows per block, one wave per row
__global__ __launch_bounds__(256) void k_ln(const float* __restrict__ hres, const float* __restrict__ lnw,
                     const float* __restrict__ lnb, float* __restrict__ xn){
  int row = blockIdx.x*4 + (threadIdx.x>>6);
  int lane = threadIdx.x & 63;
  const float* hp = hres + (size_t)row*128;
  float v0 = hp[lane], v1 = hp[lane+64];
  float s = v0+v1, q = v0*v0+v1*v1;
  #pragma unroll
  for (int off=32; off>0; off>>=1){
    s += __shfl_xor(s, off, 64);
    q += __shfl_xor(q, off, 64);
  }
  float mu = s*(1.f/128.f);
  float rs = rsqrtf(q*(1.f/128.f)-mu*mu + 1e-5f);
  float* xp = xn + (size_t)row*128;
  xp[lane]    = (v0-mu)*rs*lnw[lane]    + lnb[lane];
  xp[lane+64] = (v1-mu)*rs*lnw[lane+64] + lnb[lane+64];
}

// ---------------------------------------------------------------------------
// GEMM in_proj: xz[row, 0:512] = xn[amap(row), 0:128] @ W^T   (W: 512x128)
// ---------------------------------------------------------------------------
__global__ __launch_bounds__(256) void k_gemm_in(const float* __restrict__ Asrc, const float* __restrict__ W,
                          float* __restrict__ C, int rev){
  const int K = 128, N = 512;
  __shared__ float As[16][68];
  __shared__ float Ws[16][68];
  int row0 = blockIdx.x*64;
  int n0 = blockIdx.y*64;
  int tid = threadIdx.x;
  int tx = tid & 15, ty = tid >> 4;
  float acc[4][4] = {};
  int lk = tid & 15;
  int lm = tid >> 4;
  for (int kb=0; kb<K; kb+=16){
    #pragma unroll
    for (int j=0;j<4;j++){
      int m = lm + 16*j;
      int r = row0 + m;
      int p = r & (Ll-1); int b = r >> 12;
      int src = (b<<12) + (rev ? (Ll-1-p) : p);
      As[lk][m] = Asrc[(size_t)src*K + kb + lk];
      Ws[lk][m] = W[(size_t)(n0+m)*K + kb + lk];
    }
    __syncthreads();
    #pragma unroll
    for (int k=0;k<16;k++){
      float4 av = *(const float4*)&As[k][ty*4];
      float4 bv = *(const float4*)&Ws[k][tx*4];
      float a[4] = {av.x,av.y,av.z,av.w};
      float bb[4] = {bv.x,bv.y,bv.z,bv.w};
      #pragma unroll
      for (int i2=0;i2<4;i2++)
        #pragma unroll
        for (int j2=0;j2<4;j2++)
          acc[i2][j2] += a[i2]*bb[j2];
    }
    __syncthreads();
  }
  #pragma unroll
  for (int i2=0;i2<4;i2++){
    float* cp = C + (size_t)(row0+ty*4+i2)*N + n0 + tx*4;
    cp[0]=acc[i2][0]; cp[1]=acc[i2][1]; cp[2]=acc[i2][2]; cp[3]=acc[i2][3];
  }
}

// Depthwise causal conv (K=4) + bias + SiLU.
__global__ void k_conv(const float* __restrict__ xz, const float* __restrict__ cw,
                       const float* __restrict__ cb, float* __restrict__ xi){
  size_t idx = (size_t)blockIdx.x*256 + threadIdx.x;  // over B*L*256
  int d = (int)(idx & 255);
  size_t row = idx >> 8;     // b*L + p
  int p = (int)(row & (Ll-1));
  float wv[4];
  #pragma unroll
  for (int k=0;k<4;k++) wv[k] = cw[d*4+k];
  float acc = cb[d];
  #pragma unroll
  for (int k=0;k<4;k++){
    int q = p-3+k;
    if (q>=0){
      long long qrow = (long long)row - 3 + k;
      acc += wv[k]*xz[qrow*512 + d];
    }
  }
  xi[idx] = acc/(1.f+__expf(-acc));
}

// x_proj: dbl[row, 0:40] = xi[row,0:256] @ xw^T.  8 rows/block.
__global__ __launch_bounds__(320) void k_xproj(const float* __restrict__ xi, const float* __restrict__ xw,
                        float* __restrict__ dbl){
  __shared__ float xs[8][256];
  int tid = threadIdx.x;
  size_t row0 = (size_t)blockIdx.x*8;
  for (int idx=tid; idx<2048; idx+=320) xs[idx>>8][idx&255] = xi[row0*256 + idx];
  __syncthreads();
  int rloc = tid/40, r = tid%40;
  if (rloc<8){
    float acc=0.f;
    for (int d2=0;d2<256;d2++) acc += xs[rloc][d2]*xw[r*256+d2];
    dbl[(row0+rloc)*40 + r] = acc;
  }
}

// dt_proj + softplus
__global__ void k_dt(const float* __restrict__ dbl, const float* __restrict__ dtw,
                     const float* __restrict__ dtb, float* __restrict__ dt){
  int row = blockIdx.x; int d = threadIdx.x;
  const float* dp = dbl + (size_t)row*40;
  float acc = dtb[d];
  #pragma unroll
  for (int r=0;r<8;r++) acc += dp[r]*dtw[d*8+r];
  float v = (acc>20.f)? acc : log1pf(__expf(acc));
  dt[(size_t)row*256 + d] = v;
}

// ---------------------------------------------------------------------------
// Chunked scan. Thread = (dg 0..15, n 0..15); d = blockIdx.y*16+dg.
// Phase 1: per-chunk (P = prod dA, Q = local scan end from h=0)
// ---------------------------------------------------------------------------
__global__ __launch_bounds__(256) void k_scan1(const float* __restrict__ dt, const float* __restrict__ dbl,
                       const float* __restrict__ xi, const float* __restrict__ Alog,
                       float* __restrict__ P, float* __restrict__ Q){
  int b = blockIdx.z, c = blockIdx.x;
  int dg = threadIdx.x >> 4, n = threadIdx.x & 15;
  int d = blockIdx.y*16 + dg;
  float A = -__expf(Alog[d*16+n]);
  size_t base = (size_t)b*Ll + (size_t)c*CH;
  const float* dtp = dt + base*256 + d;
  const float* xip = xi + base*256 + d;
  const float* blp = dbl + base*40;
  float h = 0.f, pr = 1.f;
  #pragma unroll 4
  for (int p=0;p<CH;p++){
    float dtv = dtp[(size_t)p*256];
    float xiv = xip[(size_t)p*256];
    float Bc  = blp[p*40 + 8 + n];
    float a = __expf(dtv*A);
    h = a*h + dtv*Bc*xiv;
    pr *= a;
  }
  size_t sidx = ((size_t)(b*NC + c))*4096 + d*16 + n;
  P[sidx] = pr; Q[sidx] = h;
}

// Phase 2: sequential combine over chunk summaries -> start state per chunk
__global__ __launch_bounds__(256) void k_scan2(const float* __restrict__ P, const float* __restrict__ Q,
                       float* __restrict__ Hs){
  int b = blockIdx.y;
  int dn = blockIdx.x*256 + threadIdx.x;   // 0..4095
  float H = 0.f;
  for (int c=0;c<NC;c++){
    size_t idx = ((size_t)(b*NC + c))*4096 + dn;
    Hs[idx] = H;
    H = P[idx]*H + Q[idx];
  }
}

// Phase 3: re-scan chunk from Hs, y-dot over n, Dp*xi, silu(z) gate, store y.
__global__ __launch_bounds__(256) void k_scan3(const float* __restrict__ dt, const float* __restrict__ dbl,
                       const float* __restrict__ xi, const float* __restrict__ Alog,
                       const float* __restrict__ Dpw, const float* __restrict__ Hs,
                       const float* __restrict__ xz, float* __restrict__ y){
  int b = blockIdx.z, c = blockIdx.x;
  int dg = threadIdx.x >> 4, n = threadIdx.x & 15;
  int d = blockIdx.y*16 + dg;
  float A = -__expf(Alog[d*16+n]);
  float Dp = Dpw[d];
  size_t base = (size_t)b*Ll + (size_t)c*CH;
  const float* dtp = dt + base*256 + d;
  const float* xip = xi + base*256 + d;
  const float* blp = dbl + base*40;
  const float* zp  = xz + base*512 + 256 + d;
  float* yp = y + base*256 + d;
  float h = Hs[((size_t)(b*NC + c))*4096 + d*16 + n];
  #pragma unroll 2
  for (int p=0;p<CH;p++){
    float dtv = dtp[(size_t)p*256];
    float xiv = xip[(size_t)p*256];
    float Bc  = blp[p*40 + 8 + n];
    float Cc  = blp[p*40 + 24 + n];
    float a = __expf(dtv*A);
    h = a*h + dtv*Bc*xiv;
    float contrib = h*Cc;
    #pragma unroll
    for (int off=8; off>0; off>>=1) contrib += __shfl_xor(contrib, off, 16);
    if (n==0){
      float z = zp[(size_t)p*512];
      float g = z/(1.f+__expf(-z));
      yp[(size_t)p*256] = (contrib + Dp*xiv)*g;
    }
  }
}

// GEMM out_proj with rev on STORE, accumulating into hres.
__global__ __launch_bounds__(256) void k_gemm_out(const float* __restrict__ Asrc, const float* __restrict__ W,
                           float* __restrict__ C, int rev){
  const int K=256, N=128;
  __shared__ float As[16][68];
  __shared__ float Ws[16][68];
  int row0 = blockIdx.x*64, n0 = blockIdx.y*64;
  int tid=threadIdx.x, tx=tid&15, ty=tid>>4;
  float acc[4][4]={};
  int lk=tid&15, lm=tid>>4;
  for (int kb=0;kb<K;kb+=16){
    #pragma unroll
    for (int j=0;j<4;j++){
      int m=lm+16*j;
      As[lk][m] = Asrc[(size_t)(row0+m)*K + kb+lk];
      Ws[lk][m] = W[(size_t)(n0+m)*K + kb+lk];
    }
    __syncthreads();
    #pragma unroll
    for (int k=0;k<16;k++){
      float4 av=*(const float4*)&As[k][ty*4];
      float4 bv=*(const float4*)&Ws[k][tx*4];
      float a[4]={av.x,av.y,av.z,av.w}, bb[4]={bv.x,bv.y,bv.z,bv.w};
      #pragma unroll
      for (int i2=0;i2<4;i2++)
        #pragma unroll
        for (int j2=0;j2<4;j2++)
          acc[i2][j2]+=a[i2]*bb[j2];
    }
    __syncthreads();
  }
  #pragma unroll
  for (int i2=0;i2<4;i2++){
    int r = row0+ty*4+i2;
    int p = r & (Ll-1), b = r >> 12;
    int dstrow = (b<<12) + (rev ? (Ll-1-p) : p);
    float* cp = C + (size_t)dstrow*N + n0 + tx*4;
    #pragma unroll
    for (int j2=0;j2<4;j2++) cp[j2] += acc[i2][j2];
  }
}

// final transpose (B,L,128) fp32 -> (B,128,L) fp32
__global__ __launch_bounds__(256) void k_final(const float* __restrict__ hres, float* __restrict__ out){
  __shared__ float tile[64*129];
  int b = blockIdx.y, l0 = blockIdx.x*64;
  int tid = threadIdx.x;
  for (int q=0;q<32;q++){
    int idx = q*256 + tid;
    int l = idx >> 7, c = idx & 127;
    tile[l*129 + c] = hres[((size_t)b*Ll + l0 + l)*128 + c];
  }
  __syncthreads();
  int lo = tid & 63; int cbase = tid >> 6;
  for (int q=0;q<32;q++){
    int c = cbase + q*4;
    out[((size_t)b*128 + c)*Ll + l0 + lo] = tile[lo*129 + c];
  }
}

extern "C" void kernel_launch(void* const* d_in, const int* in_sizes, int n_in,
                              void* d_out, int out_size, void* d_ws, size_t ws_size,
                              hipStream_t stream){
  const float* x      = (const float*)d_in[0];
  const float* skip   = (const float*)d_in[1];
  const float* up_w   = (const float*)d_in[2];
  const float* up_b   = (const float*)d_in[3];
  const float* fus_w  = (const float*)d_in[4];
  const float* fus_b  = (const float*)d_in[5];
  const float* gn_w   = (const float*)d_in[6];
  const float* gn_b   = (const float*)d_in[7];
  const float* pa     = (const float*)d_in[8];
  const float* ln_w   = (const float*)d_in[9];
  const float* ln_b   = (const float*)d_in[10];
  const float* in_w   = (const float*)d_in[11];
  const float* conv_w = (const float*)d_in[12];
  const float* conv_b = (const float*)d_in[13];
  const float* xproj_w= (const float*)d_in[14];
  const float* dtproj_w=(const float*)d_in[15];
  const float* dtproj_b=(const float*)d_in[16];
  const float* A_log  = (const float*)d_in[17];
  const float* Dp     = (const float*)d_in[18];
  const float* out_w  = (const float*)d_in[19];

  float* w = (float*)d_ws;
  size_t off=0;
  float* AE = w+off; off += 256*3*128;
  float* AO = w+off; off += 256*2*128;
  float* FWS= w+off; off += 128*128;
  float* B2 = w+off; off += 128;
  float* GST= w+off; off += 16;
  float* H0 = w+off; off += (size_t)Bsz*Ll*128;
  float* HR = w+off; off += (size_t)Bsz*Ll*128;
  float* XN = w+off; off += (size_t)Bsz*Ll*128;
  float* XZ = w+off; off += (size_t)Bsz*Ll*512;
  float* XI = w+off; off += (size_t)Bsz*Ll*256;
  float* DBL= w+off; off += (size_t)Bsz*Ll*40;
  float* DTT= w+off; off += (size_t)Bsz*Ll*256;
  float* Y  = w+off; off += (size_t)Bsz*Ll*256;
  float* SP = w+off; off += (size_t)Bsz*NC*4096;   // chunk prod
  float* SQ = w+off; off += (size_t)Bsz*NC*4096;   // chunk partial
  float* SH = w+off; off += (size_t)Bsz*NC*4096;   // chunk start state

  hipMemsetAsync(GST, 0, 16*sizeof(float), stream);
  k_compose<<<256,128,0,stream>>>(up_w, fus_w, fus_b, up_b, AE, AO, FWS, B2);
  k_fuse<<<dim3(Tt/4,Bsz),128,0,stream>>>(x, skip, AE, AO, FWS, B2, H0, GST);
  k_gnfin<<<1,64,0,stream>>>(GST);
  k_gnapply<<<8192,256,0,stream>>>(H0, gn_w, gn_b, pa, GST, HR);
  for (int i=0;i<2;i++){
    k_ln<<<Bsz*Ll/4,256,0,stream>>>(HR, ln_w + i*128, ln_b + i*128, XN);
    for (int dir=0;dir<2;dir++){
      int br = i*2+dir;
      k_gemm_in<<<dim3(256,8),256,0,stream>>>(XN, in_w + (size_t)br*512*128, XZ, dir);
      k_conv<<<Bsz*Ll,256,0,stream>>>(XZ, conv_w + br*256*4, conv_b + br*256, XI);
      k_xproj<<<Bsz*Ll/8,320,0,stream>>>(XI, xproj_w + br*40*256, DBL);
      k_dt<<<Bsz*Ll,256,0,stream>>>(DBL, dtproj_w + br*256*8, dtproj_b + br*256, DTT);
      k_scan1<<<dim3(NC,16,Bsz),256,0,stream>>>(DTT, DBL, XI, A_log + br*256*16, SP, SQ);
      k_scan2<<<dim3(16,Bsz),256,0,stream>>>(SP, SQ, SH);
      k_scan3<<<dim3(NC,16,Bsz),256,0,stream>>>(DTT, DBL, XI, A_log + br*256*16, Dp + br*256, SH, XZ, Y);
      k_gemm_out<<<dim3(256,2),256,0,stream>>>(Y, out_w + (size_t)br*128*256, HR, dir);
    }
  }
  k_final<<<dim3(Ll/64,Bsz),256,0,stream>>>(HR, (float*)d_out);
}

// Round 4
// 1493.386 us; speedup vs baseline: 5.3066x; 1.0248x over previous
//
#include <hip/hip_runtime.h>
#include <hip/hip_bf16.h>

#define Bsz 4
#define Tt 2048
#define Ll 4096
#define NC 64      // chunks for scan
#define CH 64      // steps per chunk (NC*CH == Ll)

typedef short bf16x8 __attribute__((ext_vector_type(8)));
typedef float f32x4 __attribute__((ext_vector_type(4)));

static __device__ __forceinline__ float bs2f(unsigned short u){
  union{float f; unsigned int i;} v; v.i = ((unsigned int)u)<<16; return v.f;
}
static __device__ __forceinline__ unsigned short f2bs(float f){
  union{float f; unsigned int i;} v; v.f = f;
  unsigned int r = (v.i + 0x7fffu + ((v.i>>16)&1u)) >> 16;
  return (unsigned short)r;
}

// fp32 -> bf16 bulk convert
__global__ void k_cvt(const float* __restrict__ src, unsigned short* __restrict__ dst, int n){
  int i = blockIdx.x*256 + threadIdx.x;
  if (i < n) dst[i] = f2bs(src[i]);
}

// ---------------------------------------------------------------------------
// Compose upsample-conv weights with fuse matmul (see round-2 notes).
// ---------------------------------------------------------------------------
__global__ void k_compose(const float* __restrict__ up_w, const float* __restrict__ fus_w,
                          const float* __restrict__ fus_b, const float* __restrict__ up_b,
                          float* __restrict__ AE, float* __restrict__ AO,
                          float* __restrict__ FWS, float* __restrict__ BIAS2){
  int i = blockIdx.x;     // 0..255
  int o = threadIdx.x;    // 0..127
  float a0=0.f,a1=0.f,a2=0.f,a3=0.f,a4=0.f;
  for (int c=0;c<256;c++){
    float f = fus_w[o*384+c];
    const float* w = up_w + ((size_t)i*256+c)*5;
    a0 += f*w[0]; a1 += f*w[1]; a2 += f*w[2];
    a3 += f*w[3]; a4 += f*w[4];
  }
  AE[(i*3+0)*128+o]=a4; AE[(i*3+1)*128+o]=a2; AE[(i*3+2)*128+o]=a0;
  AO[(i*2+0)*128+o]=a3; AO[(i*2+1)*128+o]=a1;
  if (i<128) FWS[i*128+o] = fus_w[o*384+256+i];
  if (i==0){
    float bb = fus_b[o];
    for (int c=0;c<256;c++) bb += fus_w[o*384+c]*up_b[c];
    BIAS2[o]=bb;
  }
}

// ---------------------------------------------------------------------------
// Fused upsample+fuse matmul. Block = (b, 8 t-values) x 128 o-threads.
// 8 t per block amortizes the 256x5 weight loads over 2x more FMAs.
// ---------------------------------------------------------------------------
__global__ __launch_bounds__(128) void k_fuse(const float* __restrict__ x, const float* __restrict__ skip,
                       const float* __restrict__ AE, const float* __restrict__ AO,
                       const float* __restrict__ FWS, const float* __restrict__ BIAS2,
                       float* __restrict__ h0, float* __restrict__ gst){
  int b = blockIdx.y;
  int t0 = blockIdx.x*8;
  int o = threadIdx.x;
  float bias = BIAS2[o];
  float acc[16];
  #pragma unroll
  for (int q=0;q<16;q++) acc[q]=bias;

  for (int i=0;i<256;i++){
    float xv[10];
    const float* xp = x + ((size_t)b*256+i)*Tt;
    #pragma unroll
    for (int j=0;j<10;j++){
      int t = t0-1+j;
      xv[j] = (t>=0 && t<Tt) ? xp[t] : 0.f;
    }
    float ae0 = AE[(i*3+0)*128+o], ae1 = AE[(i*3+1)*128+o], ae2 = AE[(i*3+2)*128+o];
    float ao0 = AO[(i*2+0)*128+o], ao1 = AO[(i*2+1)*128+o];
    #pragma unroll
    for (int tt=0;tt<8;tt++){
      acc[2*tt]   += xv[tt]*ae0 + xv[tt+1]*ae1 + xv[tt+2]*ae2;
      acc[2*tt+1] += xv[tt+1]*ao0 + xv[tt+2]*ao1;
    }
  }
  for (int s=0;s<128;s++){
    float f = FWS[s*128+o];
    const float* sp = skip + ((size_t)b*128+s)*Ll + 2*t0;
    #pragma unroll
    for (int q=0;q<4;q++){
      float4 sv = *(const float4*)&sp[q*4];
      acc[4*q]   += f*sv.x; acc[4*q+1] += f*sv.y;
      acc[4*q+2] += f*sv.z; acc[4*q+3] += f*sv.w;
    }
  }
  float s1=0.f, s2=0.f;
  #pragma unroll
  for (int q=0;q<16;q++){
    int l = 2*t0+q;
    h0[((size_t)b*Ll + l)*128 + o] = acc[q];
    s1 += acc[q]; s2 += acc[q]*acc[q];
  }
  __shared__ float red0[128], red1[128];
  red0[o]=s1; red1[o]=s2;
  __syncthreads();
  for (int st=64; st>0; st>>=1){
    if (o<st){ red0[o]+=red0[o+st]; red1[o]+=red1[o+st]; }
    __syncthreads();
  }
  if (o==0){ atomicAdd(&gst[b*2], red0[0]); atomicAdd(&gst[b*2+1], red1[0]); }
}

__global__ void k_gnfin(float* gst){
  int b = threadIdx.x;
  if (b < Bsz){
    float n = (float)Ll*128.f;
    float mu = gst[b*2]/n;
    float var = gst[b*2+1]/n - mu*mu;
    gst[8+b]=mu; gst[12+b]=rsqrtf(var+1e-5f);
  }
}

__global__ void k_gnapply(const float* __restrict__ h0, const float* __restrict__ gn_w,
                          const float* __restrict__ gn_b, const float* __restrict__ pa,
                          const float* __restrict__ gst, float* __restrict__ hres){
  size_t idx = (size_t)blockIdx.x*256 + threadIdx.x;
  int c = (int)(idx & 127);
  int b = (int)(idx >> 19);   // L*128 = 2^19
  float mu = gst[8+b], inv = gst[12+b];
  float a = pa[0];
  float v = (h0[idx]-mu)*inv*gn_w[c] + gn_b[c];
  hres[idx] = v>=0.f ? v : a*v;
}

// LayerNorm over 128 ch; 4 rows/block, one wave per row. Writes bf16 XN.
__global__ __launch_bounds__(256) void k_ln(const float* __restrict__ hres, const float* __restrict__ lnw,
                     const float* __restrict__ lnb, unsigned short* __restrict__ xn){
  int row = blockIdx.x*4 + (threadIdx.x>>6);
  int lane = threadIdx.x & 63;
  const float* hp = hres + (size_t)row*128;
  float v0 = hp[lane], v1 = hp[lane+64];
  float s = v0+v1, q = v0*v0+v1*v1;
  #pragma unroll
  for (int off=32; off>0; off>>=1){
    s += __shfl_xor(s, off, 64);
    q += __shfl_xor(q, off, 64);
  }
  float mu = s*(1.f/128.f);
  float rs = rsqrtf(q*(1.f/128.f)-mu*mu + 1e-5f);
  unsigned short* xp = xn + (size_t)row*128;
  xp[lane]    = f2bs((v0-mu)*rs*lnw[lane]    + lnb[lane]);
  xp[lane+64] = f2bs((v1-mu)*rs*lnw[lane+64] + lnb[lane+64]);
}

// ---------------------------------------------------------------------------
// MFMA GEMM in_proj: XZB[row,0:512](bf16) = XN[amap(row),0:128](bf16) @ W^T
// Block tile 128x128, 4 waves (2x2), wave tile 64x64 = 4x4 mfma 16x16x32.
// K=128 staged in 2 chunks of 64. LDS pitch 72 shorts (16B-aligned, 2-way max).
// ---------------------------------------------------------------------------
__global__ __launch_bounds__(256) void k_gemm_in(const unsigned short* __restrict__ A,
                          const unsigned short* __restrict__ W,
                          unsigned short* __restrict__ C, int rev){
  __shared__ unsigned short As[128*72];
  __shared__ unsigned short Bs[128*72];
  int tid = threadIdx.x;
  int row0 = blockIdx.x*128;
  int n0   = blockIdx.y*128;
  int wave = tid>>6, lane = tid&63;
  int wm = wave>>1, wn = wave&1;
  int quad = lane>>4, l16 = lane&15;
  f32x4 acc[4][4];
  #pragma unroll
  for (int i=0;i<4;i++)
    #pragma unroll
    for (int j=0;j<4;j++) acc[i][j] = (f32x4){0.f,0.f,0.f,0.f};

  for (int kb=0; kb<128; kb+=64){
    __syncthreads();
    #pragma unroll
    for (int it=0; it<4; it++){
      int idx = it*256 + tid;           // 0..1023
      int row = idx>>3, c8 = idx&7;
      int r = row0 + row;
      int p = r & (Ll-1); int bb = r >> 12;
      int src = (bb<<12) + (rev ? (Ll-1-p) : p);
      *(uint4*)&As[row*72 + c8*8] = *(const uint4*)&A[(size_t)src*128 + kb + c8*8];
      *(uint4*)&Bs[row*72 + c8*8] = *(const uint4*)&W[(size_t)(n0+row)*128 + kb + c8*8];
    }
    __syncthreads();
    #pragma unroll
    for (int ks=0; ks<64; ks+=32){
      bf16x8 af[4], bf[4];
      #pragma unroll
      for (int mt=0;mt<4;mt++)
        af[mt] = *(bf16x8*)&As[(wm*64+mt*16+l16)*72 + ks + quad*8];
      #pragma unroll
      for (int nt=0;nt<4;nt++)
        bf[nt] = *(bf16x8*)&Bs[(wn*64+nt*16+l16)*72 + ks + quad*8];
      #pragma unroll
      for (int mt=0;mt<4;mt++)
        #pragma unroll
        for (int nt=0;nt<4;nt++)
          acc[mt][nt] = __builtin_amdgcn_mfma_f32_16x16x32_bf16(af[mt], bf[nt], acc[mt][nt], 0,0,0);
    }
  }
  #pragma unroll
  for (int mt=0;mt<4;mt++)
    #pragma unroll
    for (int nt=0;nt<4;nt++)
      #pragma unroll
      for (int r=0;r<4;r++){
        int row = row0 + wm*64 + mt*16 + quad*4 + r;
        int col = n0 + wn*64 + nt*16 + l16;
        C[(size_t)row*512 + col] = f2bs(acc[mt][nt][r]);
      }
}

// ---------------------------------------------------------------------------
// MFMA GEMM out_proj: HR[amap(row),0:128] += Y[row,0:256](bf16) @ W^T
// Same structure; K=256 in 4 chunks of 64; rev applied on STORE.
// ---------------------------------------------------------------------------
__global__ __launch_bounds__(256) void k_gemm_out(const unsigned short* __restrict__ A,
                           const unsigned short* __restrict__ W,
                           float* __restrict__ C, int rev){
  __shared__ unsigned short As[128*72];
  __shared__ unsigned short Bs[128*72];
  int tid = threadIdx.x;
  int row0 = blockIdx.x*128;
  int wave = tid>>6, lane = tid&63;
  int wm = wave>>1, wn = wave&1;
  int quad = lane>>4, l16 = lane&15;
  f32x4 acc[4][4];
  #pragma unroll
  for (int i=0;i<4;i++)
    #pragma unroll
    for (int j=0;j<4;j++) acc[i][j] = (f32x4){0.f,0.f,0.f,0.f};

  for (int kb=0; kb<256; kb+=64){
    __syncthreads();
    #pragma unroll
    for (int it=0; it<4; it++){
      int idx = it*256 + tid;
      int row = idx>>3, c8 = idx&7;
      *(uint4*)&As[row*72 + c8*8] = *(const uint4*)&A[(size_t)(row0+row)*256 + kb + c8*8];
      *(uint4*)&Bs[row*72 + c8*8] = *(const uint4*)&W[(size_t)row*256 + kb + c8*8];
    }
    __syncthreads();
    #pragma unroll
    for (int ks=0; ks<64; ks+=32){
      bf16x8 af[4], bf[4];
      #pragma unroll
      for (int mt=0;mt<4;mt++)
        af[mt] = *(bf16x8*)&As[(wm*64+mt*16+l16)*72 + ks + quad*8];
      #pragma unroll
      for (int nt=0;nt<4;nt++)
        bf[nt] = *(bf16x8*)&Bs[(wn*64+nt*16+l16)*72 + ks + quad*8];
      #pragma unroll
      for (int mt=0;mt<4;mt++)
        #pragma unroll
        for (int nt=0;nt<4;nt++)
          acc[mt][nt] = __builtin_amdgcn_mfma_f32_16x16x32_bf16(af[mt], bf[nt], acc[mt][nt], 0,0,0);
    }
  }
  #pragma unroll
  for (int mt=0;mt<4;mt++)
    #pragma unroll
    for (int nt=0;nt<4;nt++)
      #pragma unroll
      for (int r=0;r<4;r++){
        int row = row0 + wm*64 + mt*16 + quad*4 + r;
        int p = row & (Ll-1), bb = row >> 12;
        int dst = (bb<<12) + (rev ? (Ll-1-p) : p);
        int col = wn*64 + nt*16 + l16;
        C[(size_t)dst*128 + col] += acc[mt][nt][r];
      }
}

// Depthwise causal conv (K=4) + bias + SiLU. Reads bf16 xz, writes fp32 xi.
__global__ void k_conv(const unsigned short* __restrict__ xz, const float* __restrict__ cw,
                       const float* __restrict__ cb, float* __restrict__ xi){
  size_t idx = (size_t)blockIdx.x*256 + threadIdx.x;  // over B*L*256
  int d = (int)(idx & 255);
  size_t row = idx >> 8;     // b*L + p
  int p = (int)(row & (Ll-1));
  float wv[4];
  #pragma unroll
  for (int k=0;k<4;k++) wv[k] = cw[d*4+k];
  float acc = cb[d];
  #pragma unroll
  for (int k=0;k<4;k++){
    int q = p-3+k;
    if (q>=0){
      long long qrow = (long long)row - 3 + k;
      acc += wv[k]*bs2f(xz[qrow*512 + d]);
    }
  }
  xi[idx] = acc/(1.f+__expf(-acc));
}

// x_proj: dbl[row,0:40] = xi[row,0:256] @ xw^T. One wave per row; weights
// LDS-transposed (lane r reads consecutive), activations shfl-broadcast.
__global__ __launch_bounds__(256) void k_xproj(const float* __restrict__ xi, const float* __restrict__ xw,
                        float* __restrict__ dbl){
  __shared__ float xwT[256*40];
  int tid = threadIdx.x;
  for (int idx=tid; idx<256*40; idx+=256){
    int k = idx/40, r = idx%40;
    xwT[idx] = xw[r*256+k];
  }
  __syncthreads();
  int w = tid>>6, lane = tid&63;
  size_t row0 = (size_t)blockIdx.x*64 + w*16;
  for (int rr=0; rr<16; rr++){
    size_t row = row0 + rr;
    float4 x4 = *(const float4*)&xi[row*256 + lane*4];
    float acc = 0.f;
    #pragma unroll 8
    for (int k4=0; k4<64; k4++){
      float v0 = __shfl(x4.x, k4, 64);
      float v1 = __shfl(x4.y, k4, 64);
      float v2 = __shfl(x4.z, k4, 64);
      float v3 = __shfl(x4.w, k4, 64);
      if (lane < 40){
        acc += v0*xwT[(k4*4+0)*40+lane] + v1*xwT[(k4*4+1)*40+lane]
             + v2*xwT[(k4*4+2)*40+lane] + v3*xwT[(k4*4+3)*40+lane];
      }
    }
    if (lane < 40) dbl[row*40 + lane] = acc;
  }
}

// dt_proj + softplus
__global__ void k_dt(const float* __restrict__ dbl, const float* __restrict__ dtw,
                     const float* __restrict__ dtb, float* __restrict__ dt){
  int row = blockIdx.x; int d = threadIdx.x;
  const float* dp = dbl + (size_t)row*40;
  float acc = dtb[d];
  #pragma unroll
  for (int r=0;r<8;r++) acc += dp[r]*dtw[d*8+r];
  float v = (acc>20.f)? acc : log1pf(__expf(acc));
  dt[(size_t)row*256 + d] = v;
}

// ---------------------------------------------------------------------------
// Chunked scan. Thread = (dg 0..15, n 0..15); d = blockIdx.y*16+dg.
// ---------------------------------------------------------------------------
__global__ __launch_bounds__(256) void k_scan1(const float* __restrict__ dt, const float* __restrict__ dbl,
                       const float* __restrict__ xi, const float* __restrict__ Alog,
                       float* __restrict__ P, float* __restrict__ Q){
  int b = blockIdx.z, c = blockIdx.x;
  int dg = threadIdx.x >> 4, n = threadIdx.x & 15;
  int d = blockIdx.y*16 + dg;
  float A = -__expf(Alog[d*16+n]);
  size_t base = (size_t)b*Ll + (size_t)c*CH;
  const float* dtp = dt + base*256 + d;
  const float* xip = xi + base*256 + d;
  const float* blp = dbl + base*40;
  float h = 0.f, pr = 1.f;
  #pragma unroll 4
  for (int p=0;p<CH;p++){
    float dtv = dtp[(size_t)p*256];
    float xiv = xip[(size_t)p*256];
    float Bc  = blp[p*40 + 8 + n];
    float a = __expf(dtv*A);
    h = a*h + dtv*Bc*xiv;
    pr *= a;
  }
  size_t sidx = ((size_t)(b*NC + c))*4096 + d*16 + n;
  P[sidx] = pr; Q[sidx] = h;
}

__global__ __launch_bounds__(256) void k_scan2(const float* __restrict__ P, const float* __restrict__ Q,
                       float* __restrict__ Hs){
  int b = blockIdx.y;
  int dn = blockIdx.x*256 + threadIdx.x;   // 0..4095
  float H = 0.f;
  for (int c=0;c<NC;c++){
    size_t idx = ((size_t)(b*NC + c))*4096 + dn;
    Hs[idx] = H;
    H = P[idx]*H + Q[idx];
  }
}

// Phase 3: re-scan from Hs, y-dot over n, +Dp*xi, silu(z) gate, bf16 y.
__global__ __launch_bounds__(256) void k_scan3(const float* __restrict__ dt, const float* __restrict__ dbl,
                       const float* __restrict__ xi, const float* __restrict__ Alog,
                       const float* __restrict__ Dpw, const float* __restrict__ Hs,
                       const unsigned short* __restrict__ xz, unsigned short* __restrict__ y){
  int b = blockIdx.z, c = blockIdx.x;
  int dg = threadIdx.x >> 4, n = threadIdx.x & 15;
  int d = blockIdx.y*16 + dg;
  float A = -__expf(Alog[d*16+n]);
  float Dp = Dpw[d];
  size_t base = (size_t)b*Ll + (size_t)c*CH;
  const float* dtp = dt + base*256 + d;
  const float* xip = xi + base*256 + d;
  const float* blp = dbl + base*40;
  const unsigned short* zp = xz + base*512 + 256 + d;
  unsigned short* yp = y + base*256 + d;
  float h = Hs[((size_t)(b*NC + c))*4096 + d*16 + n];
  #pragma unroll 2
  for (int p=0;p<CH;p++){
    float dtv = dtp[(size_t)p*256];
    float xiv = xip[(size_t)p*256];
    float Bc  = blp[p*40 + 8 + n];
    float Cc  = blp[p*40 + 24 + n];
    float a = __expf(dtv*A);
    h = a*h + dtv*Bc*xiv;
    float contrib = h*Cc;
    #pragma unroll
    for (int off=8; off>0; off>>=1) contrib += __shfl_xor(contrib, off, 16);
    if (n==0){
      float z = bs2f(zp[(size_t)p*512]);
      float g = z/(1.f+__expf(-z));
      yp[(size_t)p*256] = f2bs((contrib + Dp*xiv)*g);
    }
  }
}

// final transpose (B,L,128) fp32 -> (B,128,L) fp32
__global__ __launch_bounds__(256) void k_final(const float* __restrict__ hres, float* __restrict__ out){
  __shared__ float tile[64*129];
  int b = blockIdx.y, l0 = blockIdx.x*64;
  int tid = threadIdx.x;
  for (int q=0;q<32;q++){
    int idx = q*256 + tid;
    int l = idx >> 7, c = idx & 127;
    tile[l*129 + c] = hres[((size_t)b*Ll + l0 + l)*128 + c];
  }
  __syncthreads();
  int lo = tid & 63; int cbase = tid >> 6;
  for (int q=0;q<32;q++){
    int c = cbase + q*4;
    out[((size_t)b*128 + c)*Ll + l0 + lo] = tile[lo*129 + c];
  }
}

extern "C" void kernel_launch(void* const* d_in, const int* in_sizes, int n_in,
                              void* d_out, int out_size, void* d_ws, size_t ws_size,
                              hipStream_t stream){
  const float* x      = (const float*)d_in[0];
  const float* skip   = (const float*)d_in[1];
  const float* up_w   = (const float*)d_in[2];
  const float* up_b   = (const float*)d_in[3];
  const float* fus_w  = (const float*)d_in[4];
  const float* fus_b  = (const float*)d_in[5];
  const float* gn_w   = (const float*)d_in[6];
  const float* gn_b   = (const float*)d_in[7];
  const float* pa     = (const float*)d_in[8];
  const float* ln_w   = (const float*)d_in[9];
  const float* ln_b   = (const float*)d_in[10];
  const float* in_w   = (const float*)d_in[11];
  const float* conv_w = (const float*)d_in[12];
  const float* conv_b = (const float*)d_in[13];
  const float* xproj_w= (const float*)d_in[14];
  const float* dtproj_w=(const float*)d_in[15];
  const float* dtproj_b=(const float*)d_in[16];
  const float* A_log  = (const float*)d_in[17];
  const float* Dp     = (const float*)d_in[18];
  const float* out_w  = (const float*)d_in[19];

  float* w = (float*)d_ws;
  size_t off=0;
  float* AE = w+off; off += 256*3*128;
  float* AO = w+off; off += 256*2*128;
  float* FWS= w+off; off += 128*128;
  float* B2 = w+off; off += 128;
  float* GST= w+off; off += 16;
  float* H0 = w+off; off += (size_t)Bsz*Ll*128;
  float* HR = w+off; off += (size_t)Bsz*Ll*128;
  float* XI = w+off; off += (size_t)Bsz*Ll*256;
  float* DBL= w+off; off += (size_t)Bsz*Ll*40;
  float* DTT= w+off; off += (size_t)Bsz*Ll*256;
  float* SP = w+off; off += (size_t)Bsz*NC*4096;
  float* SQ = w+off; off += (size_t)Bsz*NC*4096;
  float* SH = w+off; off += (size_t)Bsz*NC*4096;
  unsigned short* XNB = (unsigned short*)(w+off); off += (size_t)Bsz*Ll*128/2;
  unsigned short* XZB = (unsigned short*)(w+off); off += (size_t)Bsz*Ll*512/2;
  unsigned short* YB  = (unsigned short*)(w+off); off += (size_t)Bsz*Ll*256/2;
  unsigned short* IWB = (unsigned short*)(w+off); off += 2*2*512*128/2;
  unsigned short* OWB = (unsigned short*)(w+off); off += 2*2*128*256/2;

  hipMemsetAsync(GST, 0, 16*sizeof(float), stream);
  k_cvt<<<(2*2*512*128+255)/256,256,0,stream>>>(in_w, IWB, 2*2*512*128);
  k_cvt<<<(2*2*128*256+255)/256,256,0,stream>>>(out_w, OWB, 2*2*128*256);
  k_compose<<<256,128,0,stream>>>(up_w, fus_w, fus_b, up_b, AE, AO, FWS, B2);
  k_fuse<<<dim3(Tt/8,Bsz),128,0,stream>>>(x, skip, AE, AO, FWS, B2, H0, GST);
  k_gnfin<<<1,64,0,stream>>>(GST);
  k_gnapply<<<8192,256,0,stream>>>(H0, gn_w, gn_b, pa, GST, HR);
  for (int i=0;i<2;i++){
    k_ln<<<Bsz*Ll/4,256,0,stream>>>(HR, ln_w + i*128, ln_b + i*128, XNB);
    for (int dir=0;dir<2;dir++){
      int br = i*2+dir;
      k_gemm_in<<<dim3(128,4),256,0,stream>>>(XNB, IWB + (size_t)br*512*128, XZB, dir);
      k_conv<<<Bsz*Ll,256,0,stream>>>(XZB, conv_w + br*256*4, conv_b + br*256, XI);
      k_xproj<<<Bsz*Ll/64,256,0,stream>>>(XI, xproj_w + br*40*256, DBL);
      k_dt<<<Bsz*Ll,256,0,stream>>>(DBL, dtproj_w + br*256*8, dtproj_b + br*256, DTT);
      k_scan1<<<dim3(NC,16,Bsz),256,0,stream>>>(DTT, DBL, XI, A_log + br*256*16, SP, SQ);
      k_scan2<<<dim3(16,Bsz),256,0,stream>>>(SP, SQ, SH);
      k_scan3<<<dim3(NC,16,Bsz),256,0,stream>>>(DTT, DBL, XI, A_log + br*256*16, Dp + br*256, SH, XZB, YB);
      k_gemm_out<<<dim3(128,1),256,0,stream>>>(YB, OWB + (size_t)br*128*256, HR, dir);
    }
  }
  k_final<<<dim3(Ll/64,Bsz),256,0,stream>>>(HR, (float*)d_out);
}

// Round 5
// 1293.031 us; speedup vs baseline: 6.1289x; 1.1549x over previous
//
#include <hip/hip_runtime.h>
#include <hip/hip_bf16.h>

#define Bsz 4
#define Tt 2048
#define Ll 4096
#define NC 64      // chunks for scan
#define CH 64      // steps per chunk (NC*CH == Ll)

typedef short bf16x8 __attribute__((ext_vector_type(8)));
typedef float f32x4 __attribute__((ext_vector_type(4)));

static __device__ __forceinline__ float bs2f(unsigned short u){
  union{float f; unsigned int i;} v; v.i = ((unsigned int)u)<<16; return v.f;
}
static __device__ __forceinline__ unsigned short f2bs(float f){
  union{float f; unsigned int i;} v; v.f = f;
  unsigned int r = (v.i + 0x7fffu + ((v.i>>16)&1u)) >> 16;
  return (unsigned short)r;
}

// fp32 -> bf16 bulk convert
__global__ void k_cvt(const float* __restrict__ src, unsigned short* __restrict__ dst, int n){
  int i = blockIdx.x*256 + threadIdx.x;
  if (i < n) dst[i] = f2bs(src[i]);
}

// ---------------------------------------------------------------------------
// Compose upsample-conv weights with fuse matmul; emit bf16 GEMM-ready layouts:
// WEb[o][tap*256+i] (K=768, taps for x[t-1],x[t],x[t+1] = up_w k 4,2,0)
// WOb[o][tap*256+i] (K=512, taps for x[t],x[t+1]       = up_w k 3,1)
// FWSb[o][s], B2[o] = fus_b[o] + sum_c fus_w[o,c]*up_b[c]
// ---------------------------------------------------------------------------
__global__ void k_compose(const float* __restrict__ up_w, const float* __restrict__ fus_w,
                          const float* __restrict__ fus_b, const float* __restrict__ up_b,
                          unsigned short* __restrict__ WEb, unsigned short* __restrict__ WOb,
                          unsigned short* __restrict__ FWSb, float* __restrict__ BIAS2){
  int i = blockIdx.x;     // 0..255
  int o = threadIdx.x;    // 0..127
  float a0=0.f,a1=0.f,a2=0.f,a3=0.f,a4=0.f;
  for (int c=0;c<256;c++){
    float f = fus_w[o*384+c];
    const float* w = up_w + ((size_t)i*256+c)*5;
    a0 += f*w[0]; a1 += f*w[1]; a2 += f*w[2];
    a3 += f*w[3]; a4 += f*w[4];
  }
  WEb[(size_t)o*768 +       i] = f2bs(a4);
  WEb[(size_t)o*768 + 256 + i] = f2bs(a2);
  WEb[(size_t)o*768 + 512 + i] = f2bs(a0);
  WOb[(size_t)o*512 +       i] = f2bs(a3);
  WOb[(size_t)o*512 + 256 + i] = f2bs(a1);
  if (i<128) FWSb[o*128 + i] = f2bs(fus_w[o*384+256+i]);
  if (i==0){
    float bb = fus_b[o];
    for (int c=0;c<256;c++) bb += fus_w[o*384+c]*up_b[c];
    BIAS2[o]=bb;
  }
}

// transpose x (B,256,T) f32 -> XT (B, T+2, 256) bf16, row t stored at t+1
__global__ __launch_bounds__(256) void k_tx(const float* __restrict__ x, unsigned short* __restrict__ XT){
  __shared__ float tile[64][65];
  int b=blockIdx.z, t0=blockIdx.x*64, i0=blockIdx.y*64;
  int tid=threadIdx.x;
  for (int it=0;it<16;it++){
    int idx=it*256+tid; int ii=idx>>6, tt=idx&63;
    tile[ii][tt] = x[((size_t)b*256+i0+ii)*Tt + t0+tt];
  }
  __syncthreads();
  for (int it=0;it<16;it++){
    int idx=it*256+tid; int tt=idx>>6, ii=idx&63;
    XT[((size_t)b*2050 + t0+tt+1)*256 + i0+ii] = f2bs(tile[ii][tt]);
  }
}

// zero XT halo rows (t=-1 and t=2048)
__global__ void k_zero(unsigned short* __restrict__ XT){
  int tid=threadIdx.x;
  for (int b=0;b<Bsz;b++){
    XT[((size_t)b*2050)*256 + tid] = 0;
    XT[((size_t)b*2050+2049)*256 + tid] = 0;
  }
}

// transpose skip (B,128,L) f32 -> SKT (B,L,128) bf16
__global__ __launch_bounds__(256) void k_ts(const float* __restrict__ skip, unsigned short* __restrict__ SKT){
  __shared__ float tile[64][65];
  int b=blockIdx.z, l0=blockIdx.x*64, s0=blockIdx.y*64;
  int tid=threadIdx.x;
  for (int it=0;it<16;it++){
    int idx=it*256+tid; int ss=idx>>6, ll=idx&63;
    tile[ss][ll] = skip[((size_t)b*128+s0+ss)*Ll + l0+ll];
  }
  __syncthreads();
  for (int it=0;it<16;it++){
    int idx=it*256+tid; int ll=idx>>6, ss=idx&63;
    SKT[((size_t)b*Ll + l0+ll)*128 + s0+ss] = f2bs(tile[ss][ll]);
  }
}

// ---------------------------------------------------------------------------
// MFMA upsample+fuse: one block = 64 t x 128 o for one parity.
// h0[2t+par][o] = sum_k XLwin[t][k] * W[o][k]  + skip-phase K=128 + bias.
// GN partial sums accumulated in epilogue.
// ---------------------------------------------------------------------------
__global__ __launch_bounds__(256) void k_up(const unsigned short* __restrict__ XT,
                     const unsigned short* __restrict__ SKT,
                     const unsigned short* __restrict__ WEb, const unsigned short* __restrict__ WOb,
                     const unsigned short* __restrict__ FWSb, const float* __restrict__ B2,
                     float* __restrict__ h0, float* __restrict__ gst){
  __shared__ unsigned short XL[66*264];
  __shared__ unsigned short Wb[128*72];
  __shared__ float red0[256], red1[256];
  int bt = blockIdx.x, par = blockIdx.y, b = blockIdx.z;
  int t0 = bt*64;
  int tid = threadIdx.x;
  int wave = tid>>6, lane = tid&63;
  int wm = wave>>1, wn = wave&1;
  int quad = lane>>4, l16 = lane&15;

  // stage XT rows t0-1 .. t0+64 (XT row = t+1 -> t0+j, j=0..65)
  for (int idx=tid; idx<66*32; idx+=256){
    int row = idx>>5, c8 = idx&31;
    *(uint4*)&XL[row*264 + c8*8] = *(const uint4*)&XT[((size_t)b*2050 + t0 + row)*256 + c8*8];
  }

  const unsigned short* Wsrc = par ? WOb : WEb;
  const int Kw = par ? 512 : 768;
  const int tapbase = par ? 1 : 0;
  f32x4 acc[2][4];
  #pragma unroll
  for (int i=0;i<2;i++)
    #pragma unroll
    for (int j=0;j<4;j++) acc[i][j] = (f32x4){0.f,0.f,0.f,0.f};

  int nch = Kw>>6;
  for (int kc=0; kc<nch; kc++){
    __syncthreads();
    #pragma unroll
    for (int it=0; it<4; it++){
      int idx = it*256+tid;           // 1024: 128 rows x 8 uint4
      int row = idx>>3, c8 = idx&7;
      *(uint4*)&Wb[row*72 + c8*8] = *(const uint4*)&Wsrc[(size_t)row*Kw + kc*64 + c8*8];
    }
    __syncthreads();
    #pragma unroll
    for (int ks=0; ks<64; ks+=32){
      int kg = kc*64 + ks;
      int tap = kg>>8, ib = kg&255;
      bf16x8 af[2], bf[4];
      #pragma unroll
      for (int mt=0;mt<2;mt++)
        af[mt] = *(bf16x8*)&XL[(wm*32+mt*16+l16 + tapbase + tap)*264 + ib + quad*8];
      #pragma unroll
      for (int nt=0;nt<4;nt++)
        bf[nt] = *(bf16x8*)&Wb[(wn*64+nt*16+l16)*72 + ks + quad*8];
      #pragma unroll
      for (int mt=0;mt<2;mt++)
        #pragma unroll
        for (int nt=0;nt<4;nt++)
          acc[mt][nt] = __builtin_amdgcn_mfma_f32_16x16x32_bf16(af[mt], bf[nt], acc[mt][nt], 0,0,0);
    }
  }

  // ---- skip phase: K=128, A = SKT rows l=2(t0+m)+par staged over XL ----
  __syncthreads();
  for (int idx=tid; idx<64*16; idx+=256){
    int row = idx>>4, c8 = idx&15;
    *(uint4*)&XL[row*136 + c8*8] = *(const uint4*)&SKT[((size_t)b*Ll + 2*(t0+row)+par)*128 + c8*8];
  }
  for (int kc=0; kc<2; kc++){
    __syncthreads();
    #pragma unroll
    for (int it=0; it<4; it++){
      int idx = it*256+tid;
      int row = idx>>3, c8 = idx&7;
      *(uint4*)&Wb[row*72 + c8*8] = *(const uint4*)&FWSb[(size_t)row*128 + kc*64 + c8*8];
    }
    __syncthreads();
    #pragma unroll
    for (int ks=0; ks<64; ks+=32){
      bf16x8 af[2], bf[4];
      #pragma unroll
      for (int mt=0;mt<2;mt++)
        af[mt] = *(bf16x8*)&XL[(wm*32+mt*16+l16)*136 + kc*64 + ks + quad*8];
      #pragma unroll
      for (int nt=0;nt<4;nt++)
        bf[nt] = *(bf16x8*)&Wb[(wn*64+nt*16+l16)*72 + ks + quad*8];
      #pragma unroll
      for (int mt=0;mt<2;mt++)
        #pragma unroll
        for (int nt=0;nt<4;nt++)
          acc[mt][nt] = __builtin_amdgcn_mfma_f32_16x16x32_bf16(af[mt], bf[nt], acc[mt][nt], 0,0,0);
    }
  }

  // ---- epilogue: bias, store h0, GN partial sums ----
  float s1=0.f, s2=0.f;
  #pragma unroll
  for (int mt=0;mt<2;mt++)
    #pragma unroll
    for (int nt=0;nt<4;nt++)
      #pragma unroll
      for (int r=0;r<4;r++){
        int m = wm*32 + mt*16 + quad*4 + r;
        int lrow = 2*(t0+m) + par;
        int col = wn*64 + nt*16 + l16;
        float v = acc[mt][nt][r] + B2[col];
        h0[((size_t)b*Ll + lrow)*128 + col] = v;
        s1 += v; s2 += v*v;
      }
  red0[tid]=s1; red1[tid]=s2;
  __syncthreads();
  for (int st=128; st>0; st>>=1){
    if (tid<st){ red0[tid]+=red0[tid+st]; red1[tid]+=red1[tid+st]; }
    __syncthreads();
  }
  if (tid==0){ atomicAdd(&gst[b*2], red0[0]); atomicAdd(&gst[b*2+1], red1[0]); }
}

__global__ void k_gnfin(float* gst){
  int b = threadIdx.x;
  if (b < Bsz){
    float n = (float)Ll*128.f;
    float mu = gst[b*2]/n;
    float var = gst[b*2+1]/n - mu*mu;
    gst[8+b]=mu; gst[12+b]=rsqrtf(var+1e-5f);
  }
}

__global__ void k_gnapply(const float* __restrict__ h0, const float* __restrict__ gn_w,
                          const float* __restrict__ gn_b, const float* __restrict__ pa,
                          const float* __restrict__ gst, float* __restrict__ hres){
  size_t idx = (size_t)blockIdx.x*256 + threadIdx.x;
  int c = (int)(idx & 127);
  int b = (int)(idx >> 19);   // L*128 = 2^19
  float mu = gst[8+b], inv = gst[12+b];
  float a = pa[0];
  float v = (h0[idx]-mu)*inv*gn_w[c] + gn_b[c];
  hres[idx] = v>=0.f ? v : a*v;
}

// LayerNorm over 128 ch; 4 rows/block, one wave per row. Writes bf16 XN.
__global__ __launch_bounds__(256) void k_ln(const float* __restrict__ hres, const float* __restrict__ lnw,
                     const float* __restrict__ lnb, unsigned short* __restrict__ xn){
  int row = blockIdx.x*4 + (threadIdx.x>>6);
  int lane = threadIdx.x & 63;
  const float* hp = hres + (size_t)row*128;
  float v0 = hp[lane], v1 = hp[lane+64];
  float s = v0+v1, q = v0*v0+v1*v1;
  #pragma unroll
  for (int off=32; off>0; off>>=1){
    s += __shfl_xor(s, off, 64);
    q += __shfl_xor(q, off, 64);
  }
  float mu = s*(1.f/128.f);
  float rs = rsqrtf(q*(1.f/128.f)-mu*mu + 1e-5f);
  unsigned short* xp = xn + (size_t)row*128;
  xp[lane]    = f2bs((v0-mu)*rs*lnw[lane]    + lnb[lane]);
  xp[lane+64] = f2bs((v1-mu)*rs*lnw[lane+64] + lnb[lane+64]);
}

// ---------------------------------------------------------------------------
// MFMA GEMM in_proj: XZB[row,0:512](bf16) = XN[amap(row),0:128](bf16) @ W^T
// ---------------------------------------------------------------------------
__global__ __launch_bounds__(256) void k_gemm_in(const unsigned short* __restrict__ A,
                          const unsigned short* __restrict__ W,
                          unsigned short* __restrict__ C, int rev){
  __shared__ unsigned short As[128*72];
  __shared__ unsigned short Bs[128*72];
  int tid = threadIdx.x;
  int row0 = blockIdx.x*128;
  int n0   = blockIdx.y*128;
  int wave = tid>>6, lane = tid&63;
  int wm = wave>>1, wn = wave&1;
  int quad = lane>>4, l16 = lane&15;
  f32x4 acc[4][4];
  #pragma unroll
  for (int i=0;i<4;i++)
    #pragma unroll
    for (int j=0;j<4;j++) acc[i][j] = (f32x4){0.f,0.f,0.f,0.f};

  for (int kb=0; kb<128; kb+=64){
    __syncthreads();
    #pragma unroll
    for (int it=0; it<4; it++){
      int idx = it*256 + tid;           // 0..1023
      int row = idx>>3, c8 = idx&7;
      int r = row0 + row;
      int p = r & (Ll-1); int bb = r >> 12;
      int src = (bb<<12) + (rev ? (Ll-1-p) : p);
      *(uint4*)&As[row*72 + c8*8] = *(const uint4*)&A[(size_t)src*128 + kb + c8*8];
      *(uint4*)&Bs[row*72 + c8*8] = *(const uint4*)&W[(size_t)(n0+row)*128 + kb + c8*8];
    }
    __syncthreads();
    #pragma unroll
    for (int ks=0; ks<64; ks+=32){
      bf16x8 af[4], bf[4];
      #pragma unroll
      for (int mt=0;mt<4;mt++)
        af[mt] = *(bf16x8*)&As[(wm*64+mt*16+l16)*72 + ks + quad*8];
      #pragma unroll
      for (int nt=0;nt<4;nt++)
        bf[nt] = *(bf16x8*)&Bs[(wn*64+nt*16+l16)*72 + ks + quad*8];
      #pragma unroll
      for (int mt=0;mt<4;mt++)
        #pragma unroll
        for (int nt=0;nt<4;nt++)
          acc[mt][nt] = __builtin_amdgcn_mfma_f32_16x16x32_bf16(af[mt], bf[nt], acc[mt][nt], 0,0,0);
    }
  }
  #pragma unroll
  for (int mt=0;mt<4;mt++)
    #pragma unroll
    for (int nt=0;nt<4;nt++)
      #pragma unroll
      for (int r=0;r<4;r++){
        int row = row0 + wm*64 + mt*16 + quad*4 + r;
        int col = n0 + wn*64 + nt*16 + l16;
        C[(size_t)row*512 + col] = f2bs(acc[mt][nt][r]);
      }
}

// ---------------------------------------------------------------------------
// MFMA GEMM out_proj: HR[amap(row),0:128] += Y[row,0:256](bf16) @ W^T
// 64-row M-tiles -> 256 blocks. rev applied on STORE.
// ---------------------------------------------------------------------------
__global__ __launch_bounds__(256) void k_gemm_out(const unsigned short* __restrict__ A,
                           const unsigned short* __restrict__ W,
                           float* __restrict__ C, int rev){
  __shared__ unsigned short As[64*72];
  __shared__ unsigned short Bs[128*72];
  int tid = threadIdx.x;
  int row0 = blockIdx.x*64;
  int wave = tid>>6, lane = tid&63;
  int wm = wave>>1, wn = wave&1;
  int quad = lane>>4, l16 = lane&15;
  f32x4 acc[2][4];
  #pragma unroll
  for (int i=0;i<2;i++)
    #pragma unroll
    for (int j=0;j<4;j++) acc[i][j] = (f32x4){0.f,0.f,0.f,0.f};

  for (int kb=0; kb<256; kb+=64){
    __syncthreads();
    #pragma unroll
    for (int it=0; it<2; it++){
      int idx = it*256 + tid;           // 512: 64 rows x 8 uint4
      int row = idx>>3, c8 = idx&7;
      *(uint4*)&As[row*72 + c8*8] = *(const uint4*)&A[(size_t)(row0+row)*256 + kb + c8*8];
    }
    #pragma unroll
    for (int it=0; it<4; it++){
      int idx = it*256 + tid;           // 1024: 128 rows x 8 uint4
      int row = idx>>3, c8 = idx&7;
      *(uint4*)&Bs[row*72 + c8*8] = *(const uint4*)&W[(size_t)row*256 + kb + c8*8];
    }
    __syncthreads();
    #pragma unroll
    for (int ks=0; ks<64; ks+=32){
      bf16x8 af[2], bf[4];
      #pragma unroll
      for (int mt=0;mt<2;mt++)
        af[mt] = *(bf16x8*)&As[(wm*32+mt*16+l16)*72 + ks + quad*8];
      #pragma unroll
      for (int nt=0;nt<4;nt++)
        bf[nt] = *(bf16x8*)&Bs[(wn*64+nt*16+l16)*72 + ks + quad*8];
      #pragma unroll
      for (int mt=0;mt<2;mt++)
        #pragma unroll
        for (int nt=0;nt<4;nt++)
          acc[mt][nt] = __builtin_amdgcn_mfma_f32_16x16x32_bf16(af[mt], bf[nt], acc[mt][nt], 0,0,0);
    }
  }
  #pragma unroll
  for (int mt=0;mt<2;mt++)
    #pragma unroll
    for (int nt=0;nt<4;nt++)
      #pragma unroll
      for (int r=0;r<4;r++){
        int row = row0 + wm*32 + mt*16 + quad*4 + r;
        int p = row & (Ll-1), bb = row >> 12;
        int dst = (bb<<12) + (rev ? (Ll-1-p) : p);
        int col = wn*64 + nt*16 + l16;
        C[(size_t)dst*128 + col] += acc[mt][nt][r];
      }
}

// Depthwise causal conv (K=4) + bias + SiLU. Reads bf16 xz, writes fp32 xi.
__global__ void k_conv(const unsigned short* __restrict__ xz, const float* __restrict__ cw,
                       const float* __restrict__ cb, float* __restrict__ xi){
  size_t idx = (size_t)blockIdx.x*256 + threadIdx.x;  // over B*L*256
  int d = (int)(idx & 255);
  size_t row = idx >> 8;     // b*L + p
  int p = (int)(row & (Ll-1));
  float wv[4];
  #pragma unroll
  for (int k=0;k<4;k++) wv[k] = cw[d*4+k];
  float acc = cb[d];
  #pragma unroll
  for (int k=0;k<4;k++){
    int q = p-3+k;
    if (q>=0){
      long long qrow = (long long)row - 3 + k;
      acc += wv[k]*bs2f(xz[qrow*512 + d]);
    }
  }
  xi[idx] = acc/(1.f+__expf(-acc));
}

// x_proj: dbl[row,0:40] = xi[row,0:256] @ xw^T.
__global__ __launch_bounds__(256) void k_xproj(const float* __restrict__ xi, const float* __restrict__ xw,
                        float* __restrict__ dbl){
  __shared__ float xwT[256*40];
  int tid = threadIdx.x;
  for (int idx=tid; idx<256*40; idx+=256){
    int k = idx/40, r = idx%40;
    xwT[idx] = xw[r*256+k];
  }
  __syncthreads();
  int w = tid>>6, lane = tid&63;
  size_t row0 = (size_t)blockIdx.x*64 + w*16;
  for (int rr=0; rr<16; rr++){
    size_t row = row0 + rr;
    float4 x4 = *(const float4*)&xi[row*256 + lane*4];
    float acc = 0.f;
    #pragma unroll 8
    for (int k4=0; k4<64; k4++){
      float v0 = __shfl(x4.x, k4, 64);
      float v1 = __shfl(x4.y, k4, 64);
      float v2 = __shfl(x4.z, k4, 64);
      float v3 = __shfl(x4.w, k4, 64);
      if (lane < 40){
        acc += v0*xwT[(k4*4+0)*40+lane] + v1*xwT[(k4*4+1)*40+lane]
             + v2*xwT[(k4*4+2)*40+lane] + v3*xwT[(k4*4+3)*40+lane];
      }
    }
    if (lane < 40) dbl[row*40 + lane] = acc;
  }
}

// dt_proj + softplus
__global__ void k_dt(const float* __restrict__ dbl, const float* __restrict__ dtw,
                     const float* __restrict__ dtb, float* __restrict__ dt){
  int row = blockIdx.x; int d = threadIdx.x;
  const float* dp = dbl + (size_t)row*40;
  float acc = dtb[d];
  #pragma unroll
  for (int r=0;r<8;r++) acc += dp[r]*dtw[d*8+r];
  float v = (acc>20.f)? acc : log1pf(__expf(acc));
  dt[(size_t)row*256 + d] = v;
}

// ---------------------------------------------------------------------------
// Chunked scan (see round-2 notes).
// ---------------------------------------------------------------------------
__global__ __launch_bounds__(256) void k_scan1(const float* __restrict__ dt, const float* __restrict__ dbl,
                       const float* __restrict__ xi, const float* __restrict__ Alog,
                       float* __restrict__ P, float* __restrict__ Q){
  int b = blockIdx.z, c = blockIdx.x;
  int dg = threadIdx.x >> 4, n = threadIdx.x & 15;
  int d = blockIdx.y*16 + dg;
  float A = -__expf(Alog[d*16+n]);
  size_t base = (size_t)b*Ll + (size_t)c*CH;
  const float* dtp = dt + base*256 + d;
  const float* xip = xi + base*256 + d;
  const float* blp = dbl + base*40;
  float h = 0.f, pr = 1.f;
  #pragma unroll 4
  for (int p=0;p<CH;p++){
    float dtv = dtp[(size_t)p*256];
    float xiv = xip[(size_t)p*256];
    float Bc  = blp[p*40 + 8 + n];
    float a = __expf(dtv*A);
    h = a*h + dtv*Bc*xiv;
    pr *= a;
  }
  size_t sidx = ((size_t)(b*NC + c))*4096 + d*16 + n;
  P[sidx] = pr; Q[sidx] = h;
}

__global__ __launch_bounds__(256) void k_scan2(const float* __restrict__ P, const float* __restrict__ Q,
                       float* __restrict__ Hs){
  int b = blockIdx.y;
  int dn = blockIdx.x*256 + threadIdx.x;   // 0..4095
  float H = 0.f;
  for (int c=0;c<NC;c++){
    size_t idx = ((size_t)(b*NC + c))*4096 + dn;
    Hs[idx] = H;
    H = P[idx]*H + Q[idx];
  }
}

__global__ __launch_bounds__(256) void k_scan3(const float* __restrict__ dt, const float* __restrict__ dbl,
                       const float* __restrict__ xi, const float* __restrict__ Alog,
                       const float* __restrict__ Dpw, const float* __restrict__ Hs,
                       const unsigned short* __restrict__ xz, unsigned short* __restrict__ y){
  int b = blockIdx.z, c = blockIdx.x;
  int dg = threadIdx.x >> 4, n = threadIdx.x & 15;
  int d = blockIdx.y*16 + dg;
  float A = -__expf(Alog[d*16+n]);
  float Dp = Dpw[d];
  size_t base = (size_t)b*Ll + (size_t)c*CH;
  const float* dtp = dt + base*256 + d;
  const float* xip = xi + base*256 + d;
  const float* blp = dbl + base*40;
  const unsigned short* zp = xz + base*512 + 256 + d;
  unsigned short* yp = y + base*256 + d;
  float h = Hs[((size_t)(b*NC + c))*4096 + d*16 + n];
  #pragma unroll 2
  for (int p=0;p<CH;p++){
    float dtv = dtp[(size_t)p*256];
    float xiv = xip[(size_t)p*256];
    float Bc  = blp[p*40 + 8 + n];
    float Cc  = blp[p*40 + 24 + n];
    float a = __expf(dtv*A);
    h = a*h + dtv*Bc*xiv;
    float contrib = h*Cc;
    #pragma unroll
    for (int off=8; off>0; off>>=1) contrib += __shfl_xor(contrib, off, 16);
    if (n==0){
      float z = bs2f(zp[(size_t)p*512]);
      float g = z/(1.f+__expf(-z));
      yp[(size_t)p*256] = f2bs((contrib + Dp*xiv)*g);
    }
  }
}

// final transpose (B,L,128) fp32 -> (B,128,L) fp32
__global__ __launch_bounds__(256) void k_final(const float* __restrict__ hres, float* __restrict__ out){
  __shared__ float tile[64*129];
  int b = blockIdx.y, l0 = blockIdx.x*64;
  int tid = threadIdx.x;
  for (int q=0;q<32;q++){
    int idx = q*256 + tid;
    int l = idx >> 7, c = idx & 127;
    tile[l*129 + c] = hres[((size_t)b*Ll + l0 + l)*128 + c];
  }
  __syncthreads();
  int lo = tid & 63; int cbase = tid >> 6;
  for (int q=0;q<32;q++){
    int c = cbase + q*4;
    out[((size_t)b*128 + c)*Ll + l0 + lo] = tile[lo*129 + c];
  }
}

extern "C" void kernel_launch(void* const* d_in, const int* in_sizes, int n_in,
                              void* d_out, int out_size, void* d_ws, size_t ws_size,
                              hipStream_t stream){
  const float* x      = (const float*)d_in[0];
  const float* skip   = (const float*)d_in[1];
  const float* up_w   = (const float*)d_in[2];
  const float* up_b   = (const float*)d_in[3];
  const float* fus_w  = (const float*)d_in[4];
  const float* fus_b  = (const float*)d_in[5];
  const float* gn_w   = (const float*)d_in[6];
  const float* gn_b   = (const float*)d_in[7];
  const float* pa     = (const float*)d_in[8];
  const float* ln_w   = (const float*)d_in[9];
  const float* ln_b   = (const float*)d_in[10];
  const float* in_w   = (const float*)d_in[11];
  const float* conv_w = (const float*)d_in[12];
  const float* conv_b = (const float*)d_in[13];
  const float* xproj_w= (const float*)d_in[14];
  const float* dtproj_w=(const float*)d_in[15];
  const float* dtproj_b=(const float*)d_in[16];
  const float* A_log  = (const float*)d_in[17];
  const float* Dp     = (const float*)d_in[18];
  const float* out_w  = (const float*)d_in[19];

  float* w = (float*)d_ws;
  size_t off=0;
  float* B2 = w+off; off += 128;
  float* GST= w+off; off += 16;
  off = (off+3)&~(size_t)3;
  float* H0 = w+off; off += (size_t)Bsz*Ll*128;
  float* HR = w+off; off += (size_t)Bsz*Ll*128;
  float* XI = w+off; off += (size_t)Bsz*Ll*256;
  float* DBL= w+off; off += (size_t)Bsz*Ll*40;
  float* DTT= w+off; off += (size_t)Bsz*Ll*256;
  float* SP = w+off; off += (size_t)Bsz*NC*4096;
  float* SQ = w+off; off += (size_t)Bsz*NC*4096;
  float* SH = w+off; off += (size_t)Bsz*NC*4096;
  unsigned short* XNB = (unsigned short*)(w+off); off += (size_t)Bsz*Ll*128/2;
  unsigned short* XZB = (unsigned short*)(w+off); off += (size_t)Bsz*Ll*512/2;
  unsigned short* YB  = (unsigned short*)(w+off); off += (size_t)Bsz*Ll*256/2;
  unsigned short* IWB = (unsigned short*)(w+off); off += 2*2*512*128/2;
  unsigned short* OWB = (unsigned short*)(w+off); off += 2*2*128*256/2;
  unsigned short* WEb = (unsigned short*)(w+off); off += 768*128/2;
  unsigned short* WOb = (unsigned short*)(w+off); off += 512*128/2;
  unsigned short* FWSb= (unsigned short*)(w+off); off += 128*128/2;
  unsigned short* XT  = (unsigned short*)(w+off); off += (size_t)Bsz*2050*256/2 + 4;
  unsigned short* SKT = (unsigned short*)(w+off); off += (size_t)Bsz*Ll*128/2;

  hipMemsetAsync(GST, 0, 16*sizeof(float), stream);
  k_cvt<<<(2*2*512*128+255)/256,256,0,stream>>>(in_w, IWB, 2*2*512*128);
  k_cvt<<<(2*2*128*256+255)/256,256,0,stream>>>(out_w, OWB, 2*2*128*256);
  k_compose<<<256,128,0,stream>>>(up_w, fus_w, fus_b, up_b, WEb, WOb, FWSb, B2);
  k_tx<<<dim3(Tt/64, 4, Bsz),256,0,stream>>>(x, XT);
  k_zero<<<1,256,0,stream>>>(XT);
  k_ts<<<dim3(Ll/64, 2, Bsz),256,0,stream>>>(skip, SKT);
  k_up<<<dim3(32, 2, Bsz),256,0,stream>>>(XT, SKT, WEb, WOb, FWSb, B2, H0, GST);
  k_gnfin<<<1,64,0,stream>>>(GST);
  k_gnapply<<<8192,256,0,stream>>>(H0, gn_w, gn_b, pa, GST, HR);
  for (int i=0;i<2;i++){
    k_ln<<<Bsz*Ll/4,256,0,stream>>>(HR, ln_w + i*128, ln_b + i*128, XNB);
    for (int dir=0;dir<2;dir++){
      int br = i*2+dir;
      k_gemm_in<<<dim3(128,4),256,0,stream>>>(XNB, IWB + (size_t)br*512*128, XZB, dir);
      k_conv<<<Bsz*Ll,256,0,stream>>>(XZB, conv_w + br*256*4, conv_b + br*256, XI);
      k_xproj<<<Bsz*Ll/64,256,0,stream>>>(XI, xproj_w + br*40*256, DBL);
      k_dt<<<Bsz*Ll,256,0,stream>>>(DBL, dtproj_w + br*256*8, dtproj_b + br*256, DTT);
      k_scan1<<<dim3(NC,16,Bsz),256,0,stream>>>(DTT, DBL, XI, A_log + br*256*16, SP, SQ);
      k_scan2<<<dim3(16,Bsz),256,0,stream>>>(SP, SQ, SH);
      k_scan3<<<dim3(NC,16,Bsz),256,0,stream>>>(DTT, DBL, XI, A_log + br*256*16, Dp + br*256, SH, XZB, YB);
      k_gemm_out<<<256,256,0,stream>>>(YB, OWB + (size_t)br*128*256, HR, dir);
    }
  }
  k_final<<<dim3(Ll/64,Bsz),256,0,stream>>>(HR, (float*)d_out);
}

// Round 6
// 1136.327 us; speedup vs baseline: 6.9741x; 1.1379x over previous
//
#include <hip/hip_runtime.h>
#include <hip/hip_bf16.h>

#define Bsz 4
#define Tt 2048
#define Ll 4096
#define NC 64      // chunks for scan
#define CH 64      // steps per chunk (NC*CH == Ll)

typedef short bf16x8 __attribute__((ext_vector_type(8)));
typedef float f32x4 __attribute__((ext_vector_type(4)));

static __device__ __forceinline__ float bs2f(unsigned short u){
  union{float f; unsigned int i;} v; v.i = ((unsigned int)u)<<16; return v.f;
}
static __device__ __forceinline__ unsigned short f2bs(float f){
  union{float f; unsigned int i;} v; v.f = f;
  unsigned int r = (v.i + 0x7fffu + ((v.i>>16)&1u)) >> 16;
  return (unsigned short)r;
}

// fp32 -> bf16 bulk convert
__global__ void k_cvt(const float* __restrict__ src, unsigned short* __restrict__ dst, int n){
  int i = blockIdx.x*256 + threadIdx.x;
  if (i < n) dst[i] = f2bs(src[i]);
}

// ---------------------------------------------------------------------------
// Compose upsample-conv weights with fuse matmul; emit bf16 GEMM-ready layouts.
// ---------------------------------------------------------------------------
__global__ void k_compose(const float* __restrict__ up_w, const float* __restrict__ fus_w,
                          const float* __restrict__ fus_b, const float* __restrict__ up_b,
                          unsigned short* __restrict__ WEb, unsigned short* __restrict__ WOb,
                          unsigned short* __restrict__ FWSb, float* __restrict__ BIAS2){
  int i = blockIdx.x;     // 0..255
  int o = threadIdx.x;    // 0..127
  float a0=0.f,a1=0.f,a2=0.f,a3=0.f,a4=0.f;
  for (int c=0;c<256;c++){
    float f = fus_w[o*384+c];
    const float* w = up_w + ((size_t)i*256+c)*5;
    a0 += f*w[0]; a1 += f*w[1]; a2 += f*w[2];
    a3 += f*w[3]; a4 += f*w[4];
  }
  WEb[(size_t)o*768 +       i] = f2bs(a4);
  WEb[(size_t)o*768 + 256 + i] = f2bs(a2);
  WEb[(size_t)o*768 + 512 + i] = f2bs(a0);
  WOb[(size_t)o*512 +       i] = f2bs(a3);
  WOb[(size_t)o*512 + 256 + i] = f2bs(a1);
  if (i<128) FWSb[o*128 + i] = f2bs(fus_w[o*384+256+i]);
  if (i==0){
    float bb = fus_b[o];
    for (int c=0;c<256;c++) bb += fus_w[o*384+c]*up_b[c];
    BIAS2[o]=bb;
  }
}

// transpose x (B,256,T) f32 -> XT (B, T+2, 256) bf16, row t stored at t+1
__global__ __launch_bounds__(256) void k_tx(const float* __restrict__ x, unsigned short* __restrict__ XT){
  __shared__ float tile[64][65];
  int b=blockIdx.z, t0=blockIdx.x*64, i0=blockIdx.y*64;
  int tid=threadIdx.x;
  for (int it=0;it<16;it++){
    int idx=it*256+tid; int ii=idx>>6, tt=idx&63;
    tile[ii][tt] = x[((size_t)b*256+i0+ii)*Tt + t0+tt];
  }
  __syncthreads();
  for (int it=0;it<16;it++){
    int idx=it*256+tid; int tt=idx>>6, ii=idx&63;
    XT[((size_t)b*2050 + t0+tt+1)*256 + i0+ii] = f2bs(tile[ii][tt]);
  }
}

// zero XT halo rows (t=-1 and t=2048)
__global__ void k_zero(unsigned short* __restrict__ XT){
  int tid=threadIdx.x;
  for (int b=0;b<Bsz;b++){
    XT[((size_t)b*2050)*256 + tid] = 0;
    XT[((size_t)b*2050+2049)*256 + tid] = 0;
  }
}

// transpose skip (B,128,L) f32 -> SKT (B,L,128) bf16
__global__ __launch_bounds__(256) void k_ts(const float* __restrict__ skip, unsigned short* __restrict__ SKT){
  __shared__ float tile[64][65];
  int b=blockIdx.z, l0=blockIdx.x*64, s0=blockIdx.y*64;
  int tid=threadIdx.x;
  for (int it=0;it<16;it++){
    int idx=it*256+tid; int ss=idx>>6, ll=idx&63;
    tile[ss][ll] = skip[((size_t)b*128+s0+ss)*Ll + l0+ll];
  }
  __syncthreads();
  for (int it=0;it<16;it++){
    int idx=it*256+tid; int ll=idx>>6, ss=idx&63;
    SKT[((size_t)b*Ll + l0+ll)*128 + s0+ss] = f2bs(tile[ss][ll]);
  }
}

// ---------------------------------------------------------------------------
// MFMA upsample+fuse (see round-4 notes). Block = 64 t x 128 o, one parity.
// ---------------------------------------------------------------------------
__global__ __launch_bounds__(256) void k_up(const unsigned short* __restrict__ XT,
                     const unsigned short* __restrict__ SKT,
                     const unsigned short* __restrict__ WEb, const unsigned short* __restrict__ WOb,
                     const unsigned short* __restrict__ FWSb, const float* __restrict__ B2,
                     float* __restrict__ h0, float* __restrict__ gst){
  __shared__ unsigned short XL[66*264];
  __shared__ unsigned short Wb[128*72];
  __shared__ float red0[256], red1[256];
  int bt = blockIdx.x, par = blockIdx.y, b = blockIdx.z;
  int t0 = bt*64;
  int tid = threadIdx.x;
  int wave = tid>>6, lane = tid&63;
  int wm = wave>>1, wn = wave&1;
  int quad = lane>>4, l16 = lane&15;

  for (int idx=tid; idx<66*32; idx+=256){
    int row = idx>>5, c8 = idx&31;
    *(uint4*)&XL[row*264 + c8*8] = *(const uint4*)&XT[((size_t)b*2050 + t0 + row)*256 + c8*8];
  }

  const unsigned short* Wsrc = par ? WOb : WEb;
  const int Kw = par ? 512 : 768;
  const int tapbase = par ? 1 : 0;
  f32x4 acc[2][4];
  #pragma unroll
  for (int i=0;i<2;i++)
    #pragma unroll
    for (int j=0;j<4;j++) acc[i][j] = (f32x4){0.f,0.f,0.f,0.f};

  int nch = Kw>>6;
  for (int kc=0; kc<nch; kc++){
    __syncthreads();
    #pragma unroll
    for (int it=0; it<4; it++){
      int idx = it*256+tid;
      int row = idx>>3, c8 = idx&7;
      *(uint4*)&Wb[row*72 + c8*8] = *(const uint4*)&Wsrc[(size_t)row*Kw + kc*64 + c8*8];
    }
    __syncthreads();
    #pragma unroll
    for (int ks=0; ks<64; ks+=32){
      int kg = kc*64 + ks;
      int tap = kg>>8, ib = kg&255;
      bf16x8 af[2], bf[4];
      #pragma unroll
      for (int mt=0;mt<2;mt++)
        af[mt] = *(bf16x8*)&XL[(wm*32+mt*16+l16 + tapbase + tap)*264 + ib + quad*8];
      #pragma unroll
      for (int nt=0;nt<4;nt++)
        bf[nt] = *(bf16x8*)&Wb[(wn*64+nt*16+l16)*72 + ks + quad*8];
      #pragma unroll
      for (int mt=0;mt<2;mt++)
        #pragma unroll
        for (int nt=0;nt<4;nt++)
          acc[mt][nt] = __builtin_amdgcn_mfma_f32_16x16x32_bf16(af[mt], bf[nt], acc[mt][nt], 0,0,0);
    }
  }

  __syncthreads();
  for (int idx=tid; idx<64*16; idx+=256){
    int row = idx>>4, c8 = idx&15;
    *(uint4*)&XL[row*136 + c8*8] = *(const uint4*)&SKT[((size_t)b*Ll + 2*(t0+row)+par)*128 + c8*8];
  }
  for (int kc=0; kc<2; kc++){
    __syncthreads();
    #pragma unroll
    for (int it=0; it<4; it++){
      int idx = it*256+tid;
      int row = idx>>3, c8 = idx&7;
      *(uint4*)&Wb[row*72 + c8*8] = *(const uint4*)&FWSb[(size_t)row*128 + kc*64 + c8*8];
    }
    __syncthreads();
    #pragma unroll
    for (int ks=0; ks<64; ks+=32){
      bf16x8 af[2], bf[4];
      #pragma unroll
      for (int mt=0;mt<2;mt++)
        af[mt] = *(bf16x8*)&XL[(wm*32+mt*16+l16)*136 + kc*64 + ks + quad*8];
      #pragma unroll
      for (int nt=0;nt<4;nt++)
        bf[nt] = *(bf16x8*)&Wb[(wn*64+nt*16+l16)*72 + ks + quad*8];
      #pragma unroll
      for (int mt=0;mt<2;mt++)
        #pragma unroll
        for (int nt=0;nt<4;nt++)
          acc[mt][nt] = __builtin_amdgcn_mfma_f32_16x16x32_bf16(af[mt], bf[nt], acc[mt][nt], 0,0,0);
    }
  }

  float s1=0.f, s2=0.f;
  #pragma unroll
  for (int mt=0;mt<2;mt++)
    #pragma unroll
    for (int nt=0;nt<4;nt++)
      #pragma unroll
      for (int r=0;r<4;r++){
        int m = wm*32 + mt*16 + quad*4 + r;
        int lrow = 2*(t0+m) + par;
        int col = wn*64 + nt*16 + l16;
        float v = acc[mt][nt][r] + B2[col];
        h0[((size_t)b*Ll + lrow)*128 + col] = v;
        s1 += v; s2 += v*v;
      }
  red0[tid]=s1; red1[tid]=s2;
  __syncthreads();
  for (int st=128; st>0; st>>=1){
    if (tid<st){ red0[tid]+=red0[tid+st]; red1[tid]+=red1[tid+st]; }
    __syncthreads();
  }
  if (tid==0){ atomicAdd(&gst[b*2], red0[0]); atomicAdd(&gst[b*2+1], red1[0]); }
}

__global__ void k_gnfin(float* gst){
  int b = threadIdx.x;
  if (b < Bsz){
    float n = (float)Ll*128.f;
    float mu = gst[b*2]/n;
    float var = gst[b*2+1]/n - mu*mu;
    gst[8+b]=mu; gst[12+b]=rsqrtf(var+1e-5f);
  }
}

__global__ void k_gnapply(const float* __restrict__ h0, const float* __restrict__ gn_w,
                          const float* __restrict__ gn_b, const float* __restrict__ pa,
                          const float* __restrict__ gst, float* __restrict__ hres){
  size_t idx = (size_t)blockIdx.x*256 + threadIdx.x;
  int c = (int)(idx & 127);
  int b = (int)(idx >> 19);   // L*128 = 2^19
  float mu = gst[8+b], inv = gst[12+b];
  float a = pa[0];
  float v = (h0[idx]-mu)*inv*gn_w[c] + gn_b[c];
  hres[idx] = v>=0.f ? v : a*v;
}

// LayerNorm over 128 ch; 4 rows/block, one wave per row. Writes bf16 XN.
__global__ __launch_bounds__(256) void k_ln(const float* __restrict__ hres, const float* __restrict__ lnw,
                     const float* __restrict__ lnb, unsigned short* __restrict__ xn){
  int row = blockIdx.x*4 + (threadIdx.x>>6);
  int lane = threadIdx.x & 63;
  const float* hp = hres + (size_t)row*128;
  float v0 = hp[lane], v1 = hp[lane+64];
  float s = v0+v1, q = v0*v0+v1*v1;
  #pragma unroll
  for (int off=32; off>0; off>>=1){
    s += __shfl_xor(s, off, 64);
    q += __shfl_xor(q, off, 64);
  }
  float mu = s*(1.f/128.f);
  float rs = rsqrtf(q*(1.f/128.f)-mu*mu + 1e-5f);
  unsigned short* xp = xn + (size_t)row*128;
  xp[lane]    = f2bs((v0-mu)*rs*lnw[lane]    + lnb[lane]);
  xp[lane+64] = f2bs((v1-mu)*rs*lnw[lane+64] + lnb[lane+64]);
}

// ---------------------------------------------------------------------------
// MFMA GEMM in_proj: XZB[row,0:512](bf16) = XN[amap(row),0:128](bf16) @ W^T
// ---------------------------------------------------------------------------
__global__ __launch_bounds__(256) void k_gemm_in(const unsigned short* __restrict__ A,
                          const unsigned short* __restrict__ W,
                          unsigned short* __restrict__ C, int rev){
  __shared__ unsigned short As[128*72];
  __shared__ unsigned short Bs[128*72];
  int tid = threadIdx.x;
  int row0 = blockIdx.x*128;
  int n0   = blockIdx.y*128;
  int wave = tid>>6, lane = tid&63;
  int wm = wave>>1, wn = wave&1;
  int quad = lane>>4, l16 = lane&15;
  f32x4 acc[4][4];
  #pragma unroll
  for (int i=0;i<4;i++)
    #pragma unroll
    for (int j=0;j<4;j++) acc[i][j] = (f32x4){0.f,0.f,0.f,0.f};

  for (int kb=0; kb<128; kb+=64){
    __syncthreads();
    #pragma unroll
    for (int it=0; it<4; it++){
      int idx = it*256 + tid;
      int row = idx>>3, c8 = idx&7;
      int r = row0 + row;
      int p = r & (Ll-1); int bb = r >> 12;
      int src = (bb<<12) + (rev ? (Ll-1-p) : p);
      *(uint4*)&As[row*72 + c8*8] = *(const uint4*)&A[(size_t)src*128 + kb + c8*8];
      *(uint4*)&Bs[row*72 + c8*8] = *(const uint4*)&W[(size_t)(n0+row)*128 + kb + c8*8];
    }
    __syncthreads();
    #pragma unroll
    for (int ks=0; ks<64; ks+=32){
      bf16x8 af[4], bf[4];
      #pragma unroll
      for (int mt=0;mt<4;mt++)
        af[mt] = *(bf16x8*)&As[(wm*64+mt*16+l16)*72 + ks + quad*8];
      #pragma unroll
      for (int nt=0;nt<4;nt++)
        bf[nt] = *(bf16x8*)&Bs[(wn*64+nt*16+l16)*72 + ks + quad*8];
      #pragma unroll
      for (int mt=0;mt<4;mt++)
        #pragma unroll
        for (int nt=0;nt<4;nt++)
          acc[mt][nt] = __builtin_amdgcn_mfma_f32_16x16x32_bf16(af[mt], bf[nt], acc[mt][nt], 0,0,0);
    }
  }
  #pragma unroll
  for (int mt=0;mt<4;mt++)
    #pragma unroll
    for (int nt=0;nt<4;nt++)
      #pragma unroll
      for (int r=0;r<4;r++){
        int row = row0 + wm*64 + mt*16 + quad*4 + r;
        int col = n0 + wn*64 + nt*16 + l16;
        C[(size_t)row*512 + col] = f2bs(acc[mt][nt][r]);
      }
}

// ---------------------------------------------------------------------------
// MFMA GEMM out_proj: HR[amap(row),0:128] += Y[row,0:256](bf16) @ W^T
// ---------------------------------------------------------------------------
__global__ __launch_bounds__(256) void k_gemm_out(const unsigned short* __restrict__ A,
                           const unsigned short* __restrict__ W,
                           float* __restrict__ C, int rev){
  __shared__ unsigned short As[64*72];
  __shared__ unsigned short Bs[128*72];
  int tid = threadIdx.x;
  int row0 = blockIdx.x*64;
  int wave = tid>>6, lane = tid&63;
  int wm = wave>>1, wn = wave&1;
  int quad = lane>>4, l16 = lane&15;
  f32x4 acc[2][4];
  #pragma unroll
  for (int i=0;i<2;i++)
    #pragma unroll
    for (int j=0;j<4;j++) acc[i][j] = (f32x4){0.f,0.f,0.f,0.f};

  for (int kb=0; kb<256; kb+=64){
    __syncthreads();
    #pragma unroll
    for (int it=0; it<2; it++){
      int idx = it*256 + tid;
      int row = idx>>3, c8 = idx&7;
      *(uint4*)&As[row*72 + c8*8] = *(const uint4*)&A[(size_t)(row0+row)*256 + kb + c8*8];
    }
    #pragma unroll
    for (int it=0; it<4; it++){
      int idx = it*256 + tid;
      int row = idx>>3, c8 = idx&7;
      *(uint4*)&Bs[row*72 + c8*8] = *(const uint4*)&W[(size_t)row*256 + kb + c8*8];
    }
    __syncthreads();
    #pragma unroll
    for (int ks=0; ks<64; ks+=32){
      bf16x8 af[2], bf[4];
      #pragma unroll
      for (int mt=0;mt<2;mt++)
        af[mt] = *(bf16x8*)&As[(wm*32+mt*16+l16)*72 + ks + quad*8];
      #pragma unroll
      for (int nt=0;nt<4;nt++)
        bf[nt] = *(bf16x8*)&Bs[(wn*64+nt*16+l16)*72 + ks + quad*8];
      #pragma unroll
      for (int mt=0;mt<2;mt++)
        #pragma unroll
        for (int nt=0;nt<4;nt++)
          acc[mt][nt] = __builtin_amdgcn_mfma_f32_16x16x32_bf16(af[mt], bf[nt], acc[mt][nt], 0,0,0);
    }
  }
  #pragma unroll
  for (int mt=0;mt<2;mt++)
    #pragma unroll
    for (int nt=0;nt<4;nt++)
      #pragma unroll
      for (int r=0;r<4;r++){
        int row = row0 + wm*32 + mt*16 + quad*4 + r;
        int p = row & (Ll-1), bb = row >> 12;
        int dst = (bb<<12) + (rev ? (Ll-1-p) : p);
        int col = wn*64 + nt*16 + l16;
        C[(size_t)dst*128 + col] += acc[mt][nt][r];
      }
}

// Depthwise causal conv (K=4) + bias + SiLU. Reads bf16 xz, writes fp32 xi.
__global__ void k_conv(const unsigned short* __restrict__ xz, const float* __restrict__ cw,
                       const float* __restrict__ cb, float* __restrict__ xi){
  size_t idx = (size_t)blockIdx.x*256 + threadIdx.x;
  int d = (int)(idx & 255);
  size_t row = idx >> 8;
  int p = (int)(row & (Ll-1));
  float wv[4];
  #pragma unroll
  for (int k=0;k<4;k++) wv[k] = cw[d*4+k];
  float acc = cb[d];
  #pragma unroll
  for (int k=0;k<4;k++){
    int q = p-3+k;
    if (q>=0){
      long long qrow = (long long)row - 3 + k;
      acc += wv[k]*bs2f(xz[qrow*512 + d]);
    }
  }
  xi[idx] = acc/(1.f+__expf(-acc));
}

// x_proj: dbl[row,0:40] = xi[row,0:256] @ xw^T.
__global__ __launch_bounds__(256) void k_xproj(const float* __restrict__ xi, const float* __restrict__ xw,
                        float* __restrict__ dbl){
  __shared__ float xwT[256*40];
  int tid = threadIdx.x;
  for (int idx=tid; idx<256*40; idx+=256){
    int k = idx/40, r = idx%40;
    xwT[idx] = xw[r*256+k];
  }
  __syncthreads();
  int w = tid>>6, lane = tid&63;
  size_t row0 = (size_t)blockIdx.x*64 + w*16;
  for (int rr=0; rr<16; rr++){
    size_t row = row0 + rr;
    float4 x4 = *(const float4*)&xi[row*256 + lane*4];
    float acc = 0.f;
    #pragma unroll 8
    for (int k4=0; k4<64; k4++){
      float v0 = __shfl(x4.x, k4, 64);
      float v1 = __shfl(x4.y, k4, 64);
      float v2 = __shfl(x4.z, k4, 64);
      float v3 = __shfl(x4.w, k4, 64);
      if (lane < 40){
        acc += v0*xwT[(k4*4+0)*40+lane] + v1*xwT[(k4*4+1)*40+lane]
             + v2*xwT[(k4*4+2)*40+lane] + v3*xwT[(k4*4+3)*40+lane];
      }
    }
    if (lane < 40) dbl[row*40 + lane] = acc;
  }
}

// dt_proj + softplus
__global__ void k_dt(const float* __restrict__ dbl, const float* __restrict__ dtw,
                     const float* __restrict__ dtb, float* __restrict__ dt){
  int row = blockIdx.x; int d = threadIdx.x;
  const float* dp = dbl + (size_t)row*40;
  float acc = dtb[d];
  #pragma unroll
  for (int r=0;r<8;r++) acc += dp[r]*dtw[d*8+r];
  float v = (acc>20.f)? acc : log1pf(__expf(acc));
  dt[(size_t)row*256 + d] = v;
}

// ---------------------------------------------------------------------------
// Chunked scan, one thread per d, n-state in registers.
// Phase 1: per-chunk (P[16] = prod a, Q[16] = local end state from h=0)
// ---------------------------------------------------------------------------
__global__ __launch_bounds__(256) void k_scan1(const float* __restrict__ dt, const float* __restrict__ dbl,
                       const float* __restrict__ xi, const float* __restrict__ Alog,
                       float* __restrict__ P, float* __restrict__ Q){
  __shared__ float BcS[CH][16];
  int b = blockIdx.y, c = blockIdx.x;
  int d = threadIdx.x;
  size_t base = (size_t)b*Ll + (size_t)c*CH;
  for (int idx=d; idx<CH*16; idx+=256){
    int p = idx>>4, n = idx&15;
    BcS[p][n] = dbl[(base+p)*40 + 8 + n];
  }
  float A[16];
  #pragma unroll
  for (int j=0;j<4;j++){
    float4 a4 = *(const float4*)&Alog[d*16 + j*4];
    A[4*j]=-__expf(a4.x); A[4*j+1]=-__expf(a4.y); A[4*j+2]=-__expf(a4.z); A[4*j+3]=-__expf(a4.w);
  }
  __syncthreads();
  float h[16], pr[16];
  #pragma unroll
  for (int n=0;n<16;n++){ h[n]=0.f; pr[n]=1.f; }
  const float* dtp = dt + base*256 + d;
  const float* xip = xi + base*256 + d;
  for (int p=0;p<CH;p++){
    float dtv = dtp[(size_t)p*256];
    float xiv = xip[(size_t)p*256];
    float dx = dtv*xiv;
    #pragma unroll
    for (int n=0;n<16;n++){
      float a = __expf(dtv*A[n]);
      h[n] = a*h[n] + BcS[p][n]*dx;
      pr[n] *= a;
    }
  }
  size_t sbase = ((size_t)(b*NC + c))*4096 + d*16;
  #pragma unroll
  for (int j=0;j<4;j++){
    *(float4*)&P[sbase + 4*j] = (float4){pr[4*j],pr[4*j+1],pr[4*j+2],pr[4*j+3]};
    *(float4*)&Q[sbase + 4*j] = (float4){h[4*j],h[4*j+1],h[4*j+2],h[4*j+3]};
  }
}

// Phase 2: sequential combine over chunk summaries -> start state per chunk
__global__ __launch_bounds__(256) void k_scan2(const float* __restrict__ P, const float* __restrict__ Q,
                       float* __restrict__ Hs){
  int b = blockIdx.y;
  int dn = blockIdx.x*256 + threadIdx.x;   // 0..4095
  float H = 0.f;
  for (int c=0;c<NC;c++){
    size_t idx = ((size_t)(b*NC + c))*4096 + dn;
    Hs[idx] = H;
    H = P[idx]*H + Q[idx];
  }
}

// Phase 3: re-scan from Hs; y = sum_n h[n]*Cc[n] + Dp*xi, gated by silu(z).
__global__ __launch_bounds__(256) void k_scan3(const float* __restrict__ dt, const float* __restrict__ dbl,
                       const float* __restrict__ xi, const float* __restrict__ Alog,
                       const float* __restrict__ Dpw, const float* __restrict__ Hs,
                       const unsigned short* __restrict__ xz, unsigned short* __restrict__ y){
  __shared__ float BcS[CH][16];
  __shared__ float CcS[CH][16];
  int b = blockIdx.y, c = blockIdx.x;
  int d = threadIdx.x;
  size_t base = (size_t)b*Ll + (size_t)c*CH;
  for (int idx=d; idx<CH*16; idx+=256){
    int p = idx>>4, n = idx&15;
    BcS[p][n] = dbl[(base+p)*40 + 8 + n];
    CcS[p][n] = dbl[(base+p)*40 + 24 + n];
  }
  float A[16];
  #pragma unroll
  for (int j=0;j<4;j++){
    float4 a4 = *(const float4*)&Alog[d*16 + j*4];
    A[4*j]=-__expf(a4.x); A[4*j+1]=-__expf(a4.y); A[4*j+2]=-__expf(a4.z); A[4*j+3]=-__expf(a4.w);
  }
  float Dp = Dpw[d];
  float h[16];
  size_t sbase = ((size_t)(b*NC + c))*4096 + d*16;
  #pragma unroll
  for (int j=0;j<4;j++){
    float4 h4 = *(const float4*)&Hs[sbase + 4*j];
    h[4*j]=h4.x; h[4*j+1]=h4.y; h[4*j+2]=h4.z; h[4*j+3]=h4.w;
  }
  __syncthreads();
  const float* dtp = dt + base*256 + d;
  const float* xip = xi + base*256 + d;
  const unsigned short* zp = xz + base*512 + 256 + d;
  unsigned short* yp = y + base*256 + d;
  for (int p=0;p<CH;p++){
    float dtv = dtp[(size_t)p*256];
    float xiv = xip[(size_t)p*256];
    float dx = dtv*xiv;
    float acc = 0.f;
    #pragma unroll
    for (int n=0;n<16;n++){
      float a = __expf(dtv*A[n]);
      h[n] = a*h[n] + BcS[p][n]*dx;
      acc += h[n]*CcS[p][n];
    }
    float z = bs2f(zp[(size_t)p*512]);
    float g = z/(1.f+__expf(-z));
    yp[(size_t)p*256] = f2bs((acc + Dp*xiv)*g);
  }
}

// final transpose (B,L,128) fp32 -> (B,128,L) fp32
__global__ __launch_bounds__(256) void k_final(const float* __restrict__ hres, float* __restrict__ out){
  __shared__ float tile[64*129];
  int b = blockIdx.y, l0 = blockIdx.x*64;
  int tid = threadIdx.x;
  for (int q=0;q<32;q++){
    int idx = q*256 + tid;
    int l = idx >> 7, c = idx & 127;
    tile[l*129 + c] = hres[((size_t)b*Ll + l0 + l)*128 + c];
  }
  __syncthreads();
  int lo = tid & 63; int cbase = tid >> 6;
  for (int q=0;q<32;q++){
    int c = cbase + q*4;
    out[((size_t)b*128 + c)*Ll + l0 + lo] = tile[lo*129 + c];
  }
}

extern "C" void kernel_launch(void* const* d_in, const int* in_sizes, int n_in,
                              void* d_out, int out_size, void* d_ws, size_t ws_size,
                              hipStream_t stream){
  const float* x      = (const float*)d_in[0];
  const float* skip   = (const float*)d_in[1];
  const float* up_w   = (const float*)d_in[2];
  const float* up_b   = (const float*)d_in[3];
  const float* fus_w  = (const float*)d_in[4];
  const float* fus_b  = (const float*)d_in[5];
  const float* gn_w   = (const float*)d_in[6];
  const float* gn_b   = (const float*)d_in[7];
  const float* pa     = (const float*)d_in[8];
  const float* ln_w   = (const float*)d_in[9];
  const float* ln_b   = (const float*)d_in[10];
  const float* in_w   = (const float*)d_in[11];
  const float* conv_w = (const float*)d_in[12];
  const float* conv_b = (const float*)d_in[13];
  const float* xproj_w= (const float*)d_in[14];
  const float* dtproj_w=(const float*)d_in[15];
  const float* dtproj_b=(const float*)d_in[16];
  const float* A_log  = (const float*)d_in[17];
  const float* Dp     = (const float*)d_in[18];
  const float* out_w  = (const float*)d_in[19];

  float* w = (float*)d_ws;
  size_t off=0;
  float* B2 = w+off; off += 128;
  float* GST= w+off; off += 16;
  off = (off+3)&~(size_t)3;
  float* H0 = w+off; off += (size_t)Bsz*Ll*128;
  float* HR = w+off; off += (size_t)Bsz*Ll*128;
  float* XI = w+off; off += (size_t)Bsz*Ll*256;
  float* DBL= w+off; off += (size_t)Bsz*Ll*40;
  float* DTT= w+off; off += (size_t)Bsz*Ll*256;
  float* SP = w+off; off += (size_t)Bsz*NC*4096;
  float* SQ = w+off; off += (size_t)Bsz*NC*4096;
  float* SH = w+off; off += (size_t)Bsz*NC*4096;
  unsigned short* XNB = (unsigned short*)(w+off); off += (size_t)Bsz*Ll*128/2;
  unsigned short* XZB = (unsigned short*)(w+off); off += (size_t)Bsz*Ll*512/2;
  unsigned short* YB  = (unsigned short*)(w+off); off += (size_t)Bsz*Ll*256/2;
  unsigned short* IWB = (unsigned short*)(w+off); off += 2*2*512*128/2;
  unsigned short* OWB = (unsigned short*)(w+off); off += 2*2*128*256/2;
  unsigned short* WEb = (unsigned short*)(w+off); off += 768*128/2;
  unsigned short* WOb = (unsigned short*)(w+off); off += 512*128/2;
  unsigned short* FWSb= (unsigned short*)(w+off); off += 128*128/2;
  unsigned short* XT  = (unsigned short*)(w+off); off += (size_t)Bsz*2050*256/2 + 4;
  unsigned short* SKT = (unsigned short*)(w+off); off += (size_t)Bsz*Ll*128/2;

  hipMemsetAsync(GST, 0, 16*sizeof(float), stream);
  k_cvt<<<(2*2*512*128+255)/256,256,0,stream>>>(in_w, IWB, 2*2*512*128);
  k_cvt<<<(2*2*128*256+255)/256,256,0,stream>>>(out_w, OWB, 2*2*128*256);
  k_compose<<<256,128,0,stream>>>(up_w, fus_w, fus_b, up_b, WEb, WOb, FWSb, B2);
  k_tx<<<dim3(Tt/64, 4, Bsz),256,0,stream>>>(x, XT);
  k_zero<<<1,256,0,stream>>>(XT);
  k_ts<<<dim3(Ll/64, 2, Bsz),256,0,stream>>>(skip, SKT);
  k_up<<<dim3(32, 2, Bsz),256,0,stream>>>(XT, SKT, WEb, WOb, FWSb, B2, H0, GST);
  k_gnfin<<<1,64,0,stream>>>(GST);
  k_gnapply<<<8192,256,0,stream>>>(H0, gn_w, gn_b, pa, GST, HR);
  for (int i=0;i<2;i++){
    k_ln<<<Bsz*Ll/4,256,0,stream>>>(HR, ln_w + i*128, ln_b + i*128, XNB);
    for (int dir=0;dir<2;dir++){
      int br = i*2+dir;
      k_gemm_in<<<dim3(128,4),256,0,stream>>>(XNB, IWB + (size_t)br*512*128, XZB, dir);
      k_conv<<<Bsz*Ll,256,0,stream>>>(XZB, conv_w + br*256*4, conv_b + br*256, XI);
      k_xproj<<<Bsz*Ll/64,256,0,stream>>>(XI, xproj_w + br*40*256, DBL);
      k_dt<<<Bsz*Ll,256,0,stream>>>(DBL, dtproj_w + br*256*8, dtproj_b + br*256, DTT);
      k_scan1<<<dim3(NC,Bsz),256,0,stream>>>(DTT, DBL, XI, A_log + br*256*16, SP, SQ);
      k_scan2<<<dim3(16,Bsz),256,0,stream>>>(SP, SQ, SH);
      k_scan3<<<dim3(NC,Bsz),256,0,stream>>>(DTT, DBL, XI, A_log + br*256*16, Dp + br*256, SH, XZB, YB);
      k_gemm_out<<<256,256,0,stream>>>(YB, OWB + (size_t)br*128*256, HR, dir);
    }
  }
  k_final<<<dim3(Ll/64,Bsz),256,0,stream>>>(HR, (float*)d_out);
}

// Round 8
// 832.118 us; speedup vs baseline: 9.5237x; 1.3656x over previous
//
#include <hip/hip_runtime.h>
#include <hip/hip_bf16.h>

#define Bsz 4
#define Tt 2048
#define Ll 4096
#define NC 64      // chunks for scan
#define CH 64      // steps per chunk (NC*CH == Ll)

typedef short bf16x8 __attribute__((ext_vector_type(8)));
typedef float f32x4 __attribute__((ext_vector_type(4)));

static __device__ __forceinline__ float bs2f(unsigned short u){
  union{float f; unsigned int i;} v; v.i = ((unsigned int)u)<<16; return v.f;
}
static __device__ __forceinline__ unsigned short f2bs(float f){
  union{float f; unsigned int i;} v; v.f = f;
  unsigned int r = (v.i + 0x7fffu + ((v.i>>16)&1u)) >> 16;
  return (unsigned short)r;
}

// fp32 -> bf16 bulk convert
__global__ void k_cvt(const float* __restrict__ src, unsigned short* __restrict__ dst, int n){
  int i = blockIdx.x*256 + threadIdx.x;
  if (i < n) dst[i] = f2bs(src[i]);
}

// pad xproj_w (4 branches, 40x256) to zero-filled 64x256 bf16
__global__ void k_prepx(const float* __restrict__ xw, unsigned short* __restrict__ wxb){
  int row = blockIdx.x, br = blockIdx.y, col = threadIdx.x;
  float v = (row < 40) ? xw[((size_t)br*40 + row)*256 + col] : 0.f;
  wxb[((size_t)br*64 + row)*256 + col] = f2bs(v);
}

// ---------------------------------------------------------------------------
// Compose upsample-conv weights with fuse matmul; emit bf16 GEMM-ready layouts.
// ---------------------------------------------------------------------------
__global__ void k_compose(const float* __restrict__ up_w, const float* __restrict__ fus_w,
                          const float* __restrict__ fus_b, const float* __restrict__ up_b,
                          unsigned short* __restrict__ WEb, unsigned short* __restrict__ WOb,
                          unsigned short* __restrict__ FWSb, float* __restrict__ BIAS2){
  int i = blockIdx.x;     // 0..255
  int o = threadIdx.x;    // 0..127
  float a0=0.f,a1=0.f,a2=0.f,a3=0.f,a4=0.f;
  for (int c=0;c<256;c++){
    float f = fus_w[o*384+c];
    const float* w = up_w + ((size_t)i*256+c)*5;
    a0 += f*w[0]; a1 += f*w[1]; a2 += f*w[2];
    a3 += f*w[3]; a4 += f*w[4];
  }
  WEb[(size_t)o*768 +       i] = f2bs(a4);
  WEb[(size_t)o*768 + 256 + i] = f2bs(a2);
  WEb[(size_t)o*768 + 512 + i] = f2bs(a0);
  WOb[(size_t)o*512 +       i] = f2bs(a3);
  WOb[(size_t)o*512 + 256 + i] = f2bs(a1);
  if (i<128) FWSb[o*128 + i] = f2bs(fus_w[o*384+256+i]);
  if (i==0){
    float bb = fus_b[o];
    for (int c=0;c<256;c++) bb += fus_w[o*384+c]*up_b[c];
    BIAS2[o]=bb;
  }
}

// transpose x (B,256,T) f32 -> XT (B, T+2, 256) bf16, row t stored at t+1
__global__ __launch_bounds__(256) void k_tx(const float* __restrict__ x, unsigned short* __restrict__ XT){
  __shared__ float tile[64][65];
  int b=blockIdx.z, t0=blockIdx.x*64, i0=blockIdx.y*64;
  int tid=threadIdx.x;
  for (int it=0;it<16;it++){
    int idx=it*256+tid; int ii=idx>>6, tt=idx&63;
    tile[ii][tt] = x[((size_t)b*256+i0+ii)*Tt + t0+tt];
  }
  __syncthreads();
  for (int it=0;it<16;it++){
    int idx=it*256+tid; int tt=idx>>6, ii=idx&63;
    XT[((size_t)b*2050 + t0+tt+1)*256 + i0+ii] = f2bs(tile[ii][tt]);
  }
}

// zero XT halo rows (t=-1 and t=2048)
__global__ void k_zero(unsigned short* __restrict__ XT){
  int tid=threadIdx.x;
  for (int b=0;b<Bsz;b++){
    XT[((size_t)b*2050)*256 + tid] = 0;
    XT[((size_t)b*2050+2049)*256 + tid] = 0;
  }
}

// transpose skip (B,128,L) f32 -> SKT (B,L,128) bf16
__global__ __launch_bounds__(256) void k_ts(const float* __restrict__ skip, unsigned short* __restrict__ SKT){
  __shared__ float tile[64][65];
  int b=blockIdx.z, l0=blockIdx.x*64, s0=blockIdx.y*64;
  int tid=threadIdx.x;
  for (int it=0;it<16;it++){
    int idx=it*256+tid; int ss=idx>>6, ll=idx&63;
    tile[ss][ll] = skip[((size_t)b*128+s0+ss)*Ll + l0+ll];
  }
  __syncthreads();
  for (int it=0;it<16;it++){
    int idx=it*256+tid; int ll=idx>>6, ss=idx&63;
    SKT[((size_t)b*Ll + l0+ll)*128 + s0+ss] = f2bs(tile[ss][ll]);
  }
}

// ---------------------------------------------------------------------------
// MFMA upsample+fuse (see round-4 notes). Block = 64 t x 128 o, one parity.
// ---------------------------------------------------------------------------
__global__ __launch_bounds__(256) void k_up(const unsigned short* __restrict__ XT,
                     const unsigned short* __restrict__ SKT,
                     const unsigned short* __restrict__ WEb, const unsigned short* __restrict__ WOb,
                     const unsigned short* __restrict__ FWSb, const float* __restrict__ B2,
                     float* __restrict__ h0, float* __restrict__ gst){
  __shared__ unsigned short XL[66*264];
  __shared__ unsigned short Wb[128*72];
  __shared__ float red0[256], red1[256];
  int bt = blockIdx.x, par = blockIdx.y, b = blockIdx.z;
  int t0 = bt*64;
  int tid = threadIdx.x;
  int wave = tid>>6, lane = tid&63;
  int wm = wave>>1, wn = wave&1;
  int quad = lane>>4, l16 = lane&15;

  for (int idx=tid; idx<66*32; idx+=256){
    int row = idx>>5, c8 = idx&31;
    *(uint4*)&XL[row*264 + c8*8] = *(const uint4*)&XT[((size_t)b*2050 + t0 + row)*256 + c8*8];
  }

  const unsigned short* Wsrc = par ? WOb : WEb;
  const int Kw = par ? 512 : 768;
  const int tapbase = par ? 1 : 0;
  f32x4 acc[2][4];
  #pragma unroll
  for (int i=0;i<2;i++)
    #pragma unroll
    for (int j=0;j<4;j++) acc[i][j] = (f32x4){0.f,0.f,0.f,0.f};

  int nch = Kw>>6;
  for (int kc=0; kc<nch; kc++){
    __syncthreads();
    #pragma unroll
    for (int it=0; it<4; it++){
      int idx = it*256+tid;
      int row = idx>>3, c8 = idx&7;
      *(uint4*)&Wb[row*72 + c8*8] = *(const uint4*)&Wsrc[(size_t)row*Kw + kc*64 + c8*8];
    }
    __syncthreads();
    #pragma unroll
    for (int ks=0; ks<64; ks+=32){
      int kg = kc*64 + ks;
      int tap = kg>>8, ib = kg&255;
      bf16x8 af[2], bf[4];
      #pragma unroll
      for (int mt=0;mt<2;mt++)
        af[mt] = *(bf16x8*)&XL[(wm*32+mt*16+l16 + tapbase + tap)*264 + ib + quad*8];
      #pragma unroll
      for (int nt=0;nt<4;nt++)
        bf[nt] = *(bf16x8*)&Wb[(wn*64+nt*16+l16)*72 + ks + quad*8];
      #pragma unroll
      for (int mt=0;mt<2;mt++)
        #pragma unroll
        for (int nt=0;nt<4;nt++)
          acc[mt][nt] = __builtin_amdgcn_mfma_f32_16x16x32_bf16(af[mt], bf[nt], acc[mt][nt], 0,0,0);
    }
  }

  __syncthreads();
  for (int idx=tid; idx<64*16; idx+=256){
    int row = idx>>4, c8 = idx&15;
    *(uint4*)&XL[row*136 + c8*8] = *(const uint4*)&SKT[((size_t)b*Ll + 2*(t0+row)+par)*128 + c8*8];
  }
  for (int kc=0; kc<2; kc++){
    __syncthreads();
    #pragma unroll
    for (int it=0; it<4; it++){
      int idx = it*256+tid;
      int row = idx>>3, c8 = idx&7;
      *(uint4*)&Wb[row*72 + c8*8] = *(const uint4*)&FWSb[(size_t)row*128 + kc*64 + c8*8];
    }
    __syncthreads();
    #pragma unroll
    for (int ks=0; ks<64; ks+=32){
      bf16x8 af[2], bf[4];
      #pragma unroll
      for (int mt=0;mt<2;mt++)
        af[mt] = *(bf16x8*)&XL[(wm*32+mt*16+l16)*136 + kc*64 + ks + quad*8];
      #pragma unroll
      for (int nt=0;nt<4;nt++)
        bf[nt] = *(bf16x8*)&Wb[(wn*64+nt*16+l16)*72 + ks + quad*8];
      #pragma unroll
      for (int mt=0;mt<2;mt++)
        #pragma unroll
        for (int nt=0;nt<4;nt++)
          acc[mt][nt] = __builtin_amdgcn_mfma_f32_16x16x32_bf16(af[mt], bf[nt], acc[mt][nt], 0,0,0);
    }
  }

  float s1=0.f, s2=0.f;
  #pragma unroll
  for (int mt=0;mt<2;mt++)
    #pragma unroll
    for (int nt=0;nt<4;nt++)
      #pragma unroll
      for (int r=0;r<4;r++){
        int m = wm*32 + mt*16 + quad*4 + r;
        int lrow = 2*(t0+m) + par;
        int col = wn*64 + nt*16 + l16;
        float v = acc[mt][nt][r] + B2[col];
        h0[((size_t)b*Ll + lrow)*128 + col] = v;
        s1 += v; s2 += v*v;
      }
  red0[tid]=s1; red1[tid]=s2;
  __syncthreads();
  for (int st=128; st>0; st>>=1){
    if (tid<st){ red0[tid]+=red0[tid+st]; red1[tid]+=red1[tid+st]; }
    __syncthreads();
  }
  if (tid==0){ atomicAdd(&gst[b*2], red0[0]); atomicAdd(&gst[b*2+1], red1[0]); }
}

__global__ void k_gnfin(float* gst){
  int b = threadIdx.x;
  if (b < Bsz){
    float n = (float)Ll*128.f;
    float mu = gst[b*2]/n;
    float var = gst[b*2+1]/n - mu*mu;
    gst[8+b]=mu; gst[12+b]=rsqrtf(var+1e-5f);
  }
}

__global__ void k_gnapply(const float* __restrict__ h0, const float* __restrict__ gn_w,
                          const float* __restrict__ gn_b, const float* __restrict__ pa,
                          const float* __restrict__ gst, float* __restrict__ hres){
  size_t idx = (size_t)blockIdx.x*256 + threadIdx.x;
  int c = (int)(idx & 127);
  int b = (int)(idx >> 19);   // L*128 = 2^19
  float mu = gst[8+b], inv = gst[12+b];
  float a = pa[0];
  float v = (h0[idx]-mu)*inv*gn_w[c] + gn_b[c];
  hres[idx] = v>=0.f ? v : a*v;
}

// LayerNorm over 128 ch; 4 rows/block, one wave per row. Writes bf16 XN.
__global__ __launch_bounds__(256) void k_ln(const float* __restrict__ hres, const float* __restrict__ lnw,
                     const float* __restrict__ lnb, unsigned short* __restrict__ xn){
  int row = blockIdx.x*4 + (threadIdx.x>>6);
  int lane = threadIdx.x & 63;
  const float* hp = hres + (size_t)row*128;
  float v0 = hp[lane], v1 = hp[lane+64];
  float s = v0+v1, q = v0*v0+v1*v1;
  #pragma unroll
  for (int off=32; off>0; off>>=1){
    s += __shfl_xor(s, off, 64);
    q += __shfl_xor(q, off, 64);
  }
  float mu = s*(1.f/128.f);
  float rs = rsqrtf(q*(1.f/128.f)-mu*mu + 1e-5f);
  unsigned short* xp = xn + (size_t)row*128;
  xp[lane]    = f2bs((v0-mu)*rs*lnw[lane]    + lnb[lane]);
  xp[lane+64] = f2bs((v1-mu)*rs*lnw[lane+64] + lnb[lane+64]);
}

// ---------------------------------------------------------------------------
// MFMA GEMM in_proj: XZB[row,0:512](bf16) = XN[amap(row),0:128](bf16) @ W^T
// ---------------------------------------------------------------------------
__global__ __launch_bounds__(256) void k_gemm_in(const unsigned short* __restrict__ A,
                          const unsigned short* __restrict__ W,
                          unsigned short* __restrict__ C, int rev){
  __shared__ unsigned short As[128*72];
  __shared__ unsigned short Bs[128*72];
  int tid = threadIdx.x;
  int row0 = blockIdx.x*128;
  int n0   = blockIdx.y*128;
  int wave = tid>>6, lane = tid&63;
  int wm = wave>>1, wn = wave&1;
  int quad = lane>>4, l16 = lane&15;
  f32x4 acc[4][4];
  #pragma unroll
  for (int i=0;i<4;i++)
    #pragma unroll
    for (int j=0;j<4;j++) acc[i][j] = (f32x4){0.f,0.f,0.f,0.f};

  for (int kb=0; kb<128; kb+=64){
    __syncthreads();
    #pragma unroll
    for (int it=0; it<4; it++){
      int idx = it*256 + tid;
      int row = idx>>3, c8 = idx&7;
      int r = row0 + row;
      int p = r & (Ll-1); int bb = r >> 12;
      int src = (bb<<12) + (rev ? (Ll-1-p) : p);
      *(uint4*)&As[row*72 + c8*8] = *(const uint4*)&A[(size_t)src*128 + kb + c8*8];
      *(uint4*)&Bs[row*72 + c8*8] = *(const uint4*)&W[(size_t)(n0+row)*128 + kb + c8*8];
    }
    __syncthreads();
    #pragma unroll
    for (int ks=0; ks<64; ks+=32){
      bf16x8 af[4], bf[4];
      #pragma unroll
      for (int mt=0;mt<4;mt++)
        af[mt] = *(bf16x8*)&As[(wm*64+mt*16+l16)*72 + ks + quad*8];
      #pragma unroll
      for (int nt=0;nt<4;nt++)
        bf[nt] = *(bf16x8*)&Bs[(wn*64+nt*16+l16)*72 + ks + quad*8];
      #pragma unroll
      for (int mt=0;mt<4;mt++)
        #pragma unroll
        for (int nt=0;nt<4;nt++)
          acc[mt][nt] = __builtin_amdgcn_mfma_f32_16x16x32_bf16(af[mt], bf[nt], acc[mt][nt], 0,0,0);
    }
  }
  #pragma unroll
  for (int mt=0;mt<4;mt++)
    #pragma unroll
    for (int nt=0;nt<4;nt++)
      #pragma unroll
      for (int r=0;r<4;r++){
        int row = row0 + wm*64 + mt*16 + quad*4 + r;
        int col = n0 + wn*64 + nt*16 + l16;
        C[(size_t)row*512 + col] = f2bs(acc[mt][nt][r]);
      }
}

// ---------------------------------------------------------------------------
// MFMA GEMM out_proj: HR[amap(row),0:128] += Y[row,0:256](bf16) @ W^T
// ---------------------------------------------------------------------------
__global__ __launch_bounds__(256) void k_gemm_out(const unsigned short* __restrict__ A,
                           const unsigned short* __restrict__ W,
                           float* __restrict__ C, int rev){
  __shared__ unsigned short As[64*72];
  __shared__ unsigned short Bs[128*72];
  int tid = threadIdx.x;
  int row0 = blockIdx.x*64;
  int wave = tid>>6, lane = tid&63;
  int wm = wave>>1, wn = wave&1;
  int quad = lane>>4, l16 = lane&15;
  f32x4 acc[2][4];
  #pragma unroll
  for (int i=0;i<2;i++)
    #pragma unroll
    for (int j=0;j<4;j++) acc[i][j] = (f32x4){0.f,0.f,0.f,0.f};

  for (int kb=0; kb<256; kb+=64){
    __syncthreads();
    #pragma unroll
    for (int it=0; it<2; it++){
      int idx = it*256 + tid;
      int row = idx>>3, c8 = idx&7;
      *(uint4*)&As[row*72 + c8*8] = *(const uint4*)&A[(size_t)(row0+row)*256 + kb + c8*8];
    }
    #pragma unroll
    for (int it=0; it<4; it++){
      int idx = it*256 + tid;
      int row = idx>>3, c8 = idx&7;
      *(uint4*)&Bs[row*72 + c8*8] = *(const uint4*)&W[(size_t)row*256 + kb + c8*8];
    }
    __syncthreads();
    #pragma unroll
    for (int ks=0; ks<64; ks+=32){
      bf16x8 af[2], bf[4];
      #pragma unroll
      for (int mt=0;mt<2;mt++)
        af[mt] = *(bf16x8*)&As[(wm*32+mt*16+l16)*72 + ks + quad*8];
      #pragma unroll
      for (int nt=0;nt<4;nt++)
        bf[nt] = *(bf16x8*)&Bs[(wn*64+nt*16+l16)*72 + ks + quad*8];
      #pragma unroll
      for (int mt=0;mt<2;mt++)
        #pragma unroll
        for (int nt=0;nt<4;nt++)
          acc[mt][nt] = __builtin_amdgcn_mfma_f32_16x16x32_bf16(af[mt], bf[nt], acc[mt][nt], 0,0,0);
    }
  }
  #pragma unroll
  for (int mt=0;mt<2;mt++)
    #pragma unroll
    for (int nt=0;nt<4;nt++)
      #pragma unroll
      for (int r=0;r<4;r++){
        int row = row0 + wm*32 + mt*16 + quad*4 + r;
        int p = row & (Ll-1), bb = row >> 12;
        int dst = (bb<<12) + (rev ? (Ll-1-p) : p);
        int col = wn*64 + nt*16 + l16;
        C[(size_t)dst*128 + col] += acc[mt][nt][r];
      }
}

// Depthwise causal conv (K=4) + bias + SiLU. One thread = 8 d's of one row.
// Writes fp32 xi (for scan) and bf16 xib (for xproj GEMM).
__global__ void k_conv(const unsigned short* __restrict__ xz, const float* __restrict__ cw,
                       const float* __restrict__ cb, float* __restrict__ xi,
                       unsigned short* __restrict__ xib){
  size_t gid = (size_t)blockIdx.x*256 + threadIdx.x;   // over B*L*32
  int d8 = (int)(gid & 31);
  size_t row = gid >> 5;
  int p = (int)(row & (Ll-1));
  int d0 = d8*8;
  float wv[8][4];
  #pragma unroll
  for (int j=0;j<8;j++){
    float4 w4 = *(const float4*)&cw[(d0+j)*4];
    wv[j][0]=w4.x; wv[j][1]=w4.y; wv[j][2]=w4.z; wv[j][3]=w4.w;
  }
  float acc[8];
  {
    float4 b0 = *(const float4*)&cb[d0];
    float4 b1 = *(const float4*)&cb[d0+4];
    acc[0]=b0.x; acc[1]=b0.y; acc[2]=b0.z; acc[3]=b0.w;
    acc[4]=b1.x; acc[5]=b1.y; acc[6]=b1.z; acc[7]=b1.w;
  }
  #pragma unroll
  for (int k=0;k<4;k++){
    int q = p-3+k;
    if (q>=0){
      uint4 v = *(const uint4*)&xz[((size_t)row-3+k)*512 + d0];
      const unsigned short* s = (const unsigned short*)&v;
      #pragma unroll
      for (int j=0;j<8;j++) acc[j] += wv[j][k]*bs2f(s[j]);
    }
  }
  float out[8];
  unsigned short ob[8];
  #pragma unroll
  for (int j=0;j<8;j++){
    float v = acc[j]/(1.f+__expf(-acc[j]));
    out[j]=v; ob[j]=f2bs(v);
  }
  *(float4*)&xi[row*256+d0]   = (float4){out[0],out[1],out[2],out[3]};
  *(float4*)&xi[row*256+d0+4] = (float4){out[4],out[5],out[6],out[7]};
  *(uint4*)&xib[row*256+d0] = *(uint4*)ob;
}

// ---------------------------------------------------------------------------
// MFMA x_proj + fused dt_proj/softplus.
// ---------------------------------------------------------------------------
__global__ __launch_bounds__(256) void k_xproj2(const unsigned short* __restrict__ xib,
                        const unsigned short* __restrict__ wxb,
                        const float* __restrict__ dtw, const float* __restrict__ dtb,
                        float* __restrict__ dbl, float* __restrict__ dtt){
  __shared__ unsigned short As[64*72];
  __shared__ unsigned short Bs[64*72];
  __shared__ float dblS[64][44];
  int tid = threadIdx.x;
  size_t row0 = (size_t)blockIdx.x*64;
  int wave = tid>>6, lane = tid&63;
  int quad = lane>>4, l16 = lane&15;
  f32x4 acc[4];
  #pragma unroll
  for (int j=0;j<4;j++) acc[j] = (f32x4){0.f,0.f,0.f,0.f};

  for (int kb=0; kb<256; kb+=64){
    __syncthreads();
    #pragma unroll
    for (int it=0; it<2; it++){
      int idx = it*256 + tid;
      int row = idx>>3, c8 = idx&7;
      *(uint4*)&As[row*72 + c8*8] = *(const uint4*)&xib[(row0+row)*256 + kb + c8*8];
      *(uint4*)&Bs[row*72 + c8*8] = *(const uint4*)&wxb[(size_t)row*256 + kb + c8*8];
    }
    __syncthreads();
    #pragma unroll
    for (int ks=0; ks<64; ks+=32){
      bf16x8 af = *(bf16x8*)&As[(wave*16+l16)*72 + ks + quad*8];
      #pragma unroll
      for (int nt=0;nt<4;nt++){
        bf16x8 bf = *(bf16x8*)&Bs[(nt*16+l16)*72 + ks + quad*8];
        acc[nt] = __builtin_amdgcn_mfma_f32_16x16x32_bf16(af, bf, acc[nt], 0,0,0);
      }
    }
  }
  #pragma unroll
  for (int nt=0;nt<4;nt++)
    #pragma unroll
    for (int r=0;r<4;r++){
      int m = wave*16 + quad*4 + r;
      int col = nt*16 + l16;
      if (col < 40){
        float v = acc[nt][r];
        dbl[(row0+m)*40 + col] = v;
        dblS[m][col] = v;
      }
    }
  __syncthreads();
  // phase B: thread = d (0..255)
  float wv[8];
  {
    float4 w0 = *(const float4*)&dtw[tid*8];
    float4 w1 = *(const float4*)&dtw[tid*8+4];
    wv[0]=w0.x; wv[1]=w0.y; wv[2]=w0.z; wv[3]=w0.w;
    wv[4]=w1.x; wv[5]=w1.y; wv[6]=w1.z; wv[7]=w1.w;
  }
  float bb = dtb[tid];
  for (int rr=0; rr<64; rr++){
    float a = bb;
    #pragma unroll
    for (int r=0;r<8;r++) a += dblS[rr][r]*wv[r];
    float v = (a>20.f)? a : log1pf(__expf(a));
    dtt[(row0+rr)*256 + tid] = v;
  }
}

// ---------------------------------------------------------------------------
// Chunked scan, one thread per d, n-state in registers.
// ---------------------------------------------------------------------------
__global__ __launch_bounds__(256) void k_scan1(const float* __restrict__ dt, const float* __restrict__ dbl,
                       const float* __restrict__ xi, const float* __restrict__ Alog,
                       float* __restrict__ P, float* __restrict__ Q){
  __shared__ float BcS[CH][16];
  int b = blockIdx.y, c = blockIdx.x;
  int d = threadIdx.x;
  size_t base = (size_t)b*Ll + (size_t)c*CH;
  for (int idx=d; idx<CH*16; idx+=256){
    int p = idx>>4, n = idx&15;
    BcS[p][n] = dbl[(base+p)*40 + 8 + n];
  }
  float A[16];
  #pragma unroll
  for (int j=0;j<4;j++){
    float4 a4 = *(const float4*)&Alog[d*16 + j*4];
    A[4*j]=-__expf(a4.x); A[4*j+1]=-__expf(a4.y); A[4*j+2]=-__expf(a4.z); A[4*j+3]=-__expf(a4.w);
  }
  __syncthreads();
  float h[16], pr[16];
  #pragma unroll
  for (int n=0;n<16;n++){ h[n]=0.f; pr[n]=1.f; }
  const float* dtp = dt + base*256 + d;
  const float* xip = xi + base*256 + d;
  for (int p=0;p<CH;p++){
    float dtv = dtp[(size_t)p*256];
    float xiv = xip[(size_t)p*256];
    float dx = dtv*xiv;
    #pragma unroll
    for (int n=0;n<16;n++){
      float a = __expf(dtv*A[n]);
      h[n] = a*h[n] + BcS[p][n]*dx;
      pr[n] *= a;
    }
  }
  size_t sbase = ((size_t)(b*NC + c))*4096 + d*16;
  #pragma unroll
  for (int j=0;j<4;j++){
    *(float4*)&P[sbase + 4*j] = (float4){pr[4*j],pr[4*j+1],pr[4*j+2],pr[4*j+3]};
    *(float4*)&Q[sbase + 4*j] = (float4){h[4*j],h[4*j+1],h[4*j+2],h[4*j+3]};
  }
}

__global__ __launch_bounds__(256) void k_scan2(const float* __restrict__ P, const float* __restrict__ Q,
                       float* __restrict__ Hs){
  int b = blockIdx.y;
  int dn = blockIdx.x*256 + threadIdx.x;   // 0..4095
  float H = 0.f;
  for (int c=0;c<NC;c++){
    size_t idx = ((size_t)(b*NC + c))*4096 + dn;
    Hs[idx] = H;
    H = P[idx]*H + Q[idx];
  }
}

__global__ __launch_bounds__(256) void k_scan3(const float* __restrict__ dt, const float* __restrict__ dbl,
                       const float* __restrict__ xi, const float* __restrict__ Alog,
                       const float* __restrict__ Dpw, const float* __restrict__ Hs,
                       const unsigned short* __restrict__ xz, unsigned short* __restrict__ y){
  __shared__ float BcS[CH][16];
  __shared__ float CcS[CH][16];
  int b = blockIdx.y, c = blockIdx.x;
  int d = threadIdx.x;
  size_t base = (size_t)b*Ll + (size_t)c*CH;
  for (int idx=d; idx<CH*16; idx+=256){
    int p = idx>>4, n = idx&15;
    BcS[p][n] = dbl[(base+p)*40 + 8 + n];
    CcS[p][n] = dbl[(base+p)*40 + 24 + n];
  }
  float A[16];
  #pragma unroll
  for (int j=0;j<4;j++){
    float4 a4 = *(const float4*)&Alog[d*16 + j*4];
    A[4*j]=-__expf(a4.x); A[4*j+1]=-__expf(a4.y); A[4*j+2]=-__expf(a4.z); A[4*j+3]=-__expf(a4.w);
  }
  float Dp = Dpw[d];
  float h[16];
  size_t sbase = ((size_t)(b*NC + c))*4096 + d*16;
  #pragma unroll
  for (int j=0;j<4;j++){
    float4 h4 = *(const float4*)&Hs[sbase + 4*j];
    h[4*j]=h4.x; h[4*j+1]=h4.y; h[4*j+2]=h4.z; h[4*j+3]=h4.w;
  }
  __syncthreads();
  const float* dtp = dt + base*256 + d;
  const float* xip = xi + base*256 + d;
  const unsigned short* zp = xz + base*512 + 256 + d;
  unsigned short* yp = y + base*256 + d;
  for (int p=0;p<CH;p++){
    float dtv = dtp[(size_t)p*256];
    float xiv = xip[(size_t)p*256];
    float dx = dtv*xiv;
    float acc = 0.f;
    #pragma unroll
    for (int n=0;n<16;n++){
      float a = __expf(dtv*A[n]);
      h[n] = a*h[n] + BcS[p][n]*dx;
      acc += h[n]*CcS[p][n];
    }
    float z = bs2f(zp[(size_t)p*512]);
    float g = z/(1.f+__expf(-z));
    yp[(size_t)p*256] = f2bs((acc + Dp*xiv)*g);
  }
}

// final transpose (B,L,128) fp32 -> (B,128,L) fp32
__global__ __launch_bounds__(256) void k_final(const float* __restrict__ hres, float* __restrict__ out){
  __shared__ float tile[64*129];
  int b = blockIdx.y, l0 = blockIdx.x*64;
  int tid = threadIdx.x;
  for (int q=0;q<32;q++){
    int idx = q*256 + tid;
    int l = idx >> 7, c = idx & 127;
    tile[l*129 + c] = hres[((size_t)b*Ll + l0 + l)*128 + c];
  }
  __syncthreads();
  int lo = tid & 63; int cbase = tid >> 6;
  for (int q=0;q<32;q++){
    int c = cbase + q*4;
    out[((size_t)b*128 + c)*Ll + l0 + lo] = tile[lo*129 + c];
  }
}

extern "C" void kernel_launch(void* const* d_in, const int* in_sizes, int n_in,
                              void* d_out, int out_size, void* d_ws, size_t ws_size,
                              hipStream_t stream){
  const float* x      = (const float*)d_in[0];
  const float* skip   = (const float*)d_in[1];
  const float* up_w   = (const float*)d_in[2];
  const float* up_b   = (const float*)d_in[3];
  const float* fus_w  = (const float*)d_in[4];
  const float* fus_b  = (const float*)d_in[5];
  const float* gn_w   = (const float*)d_in[6];
  const float* gn_b   = (const float*)d_in[7];
  const float* pa     = (const float*)d_in[8];
  const float* ln_w   = (const float*)d_in[9];
  const float* ln_b   = (const float*)d_in[10];
  const float* in_w   = (const float*)d_in[11];
  const float* conv_w = (const float*)d_in[12];
  const float* conv_b = (const float*)d_in[13];
  const float* xproj_w= (const float*)d_in[14];
  const float* dtproj_w=(const float*)d_in[15];
  const float* dtproj_b=(const float*)d_in[16];
  const float* A_log  = (const float*)d_in[17];
  const float* Dp     = (const float*)d_in[18];
  const float* out_w  = (const float*)d_in[19];

  // Workspace layout. ws_size is ~100 MiB (round-7 post-mortem: 108 MB layout
  // corrupted harness memory; 99.85 MB was fine). Two lifetime unions keep the
  // total at 92 MiB:
  //   U1: XT+SKT (preamble only) / SP,SQ,SH (mamba loop only)
  //   U2: H0 (preamble only)     / XIB (mamba loop only)
  float* w = (float*)d_ws;
  size_t off=0;
  float* B2 = w+off; off += 128;
  float* GST= w+off; off += 16;
  off = (off+3)&~(size_t)3;
  float* HR = w+off; off += (size_t)Bsz*Ll*128;
  float* XI = w+off; off += (size_t)Bsz*Ll*256;
  float* DBL= w+off; off += (size_t)Bsz*Ll*40;
  float* DTT= w+off; off += (size_t)Bsz*Ll*256;
  unsigned short* XNB = (unsigned short*)(w+off); off += (size_t)Bsz*Ll*128/2;
  unsigned short* XZB = (unsigned short*)(w+off); off += (size_t)Bsz*Ll*512/2;
  unsigned short* YB  = (unsigned short*)(w+off); off += (size_t)Bsz*Ll*256/2;
  unsigned short* IWB = (unsigned short*)(w+off); off += 2*2*512*128/2;
  unsigned short* OWB = (unsigned short*)(w+off); off += 2*2*128*256/2;
  unsigned short* WXB = (unsigned short*)(w+off); off += 2*2*64*256/2;
  unsigned short* WEb = (unsigned short*)(w+off); off += 768*128/2;
  unsigned short* WOb = (unsigned short*)(w+off); off += 512*128/2;
  unsigned short* FWSb= (unsigned short*)(w+off); off += 128*128/2;
  // U1: max(XT 1,049,604 + SKT 1,048,576, SP+SQ+SH 3,145,728) = 3,145,728
  float* U1 = w+off; off += 3145728;
  unsigned short* XT  = (unsigned short*)U1;
  unsigned short* SKT = (unsigned short*)(U1 + 1049604);
  float* SP = U1;
  float* SQ = U1 + 1048576;
  float* SH = U1 + 2097152;
  // U2: max(H0, XIB) = 2,097,152 floats
  float* U2 = w+off; off += (size_t)Bsz*Ll*128;
  float* H0 = U2;
  unsigned short* XIB = (unsigned short*)U2;

  hipMemsetAsync(GST, 0, 16*sizeof(float), stream);
  k_cvt<<<(2*2*512*128+255)/256,256,0,stream>>>(in_w, IWB, 2*2*512*128);
  k_cvt<<<(2*2*128*256+255)/256,256,0,stream>>>(out_w, OWB, 2*2*128*256);
  k_prepx<<<dim3(64,4),256,0,stream>>>(xproj_w, WXB);
  k_compose<<<256,128,0,stream>>>(up_w, fus_w, fus_b, up_b, WEb, WOb, FWSb, B2);
  k_tx<<<dim3(Tt/64, 4, Bsz),256,0,stream>>>(x, XT);
  k_zero<<<1,256,0,stream>>>(XT);
  k_ts<<<dim3(Ll/64, 2, Bsz),256,0,stream>>>(skip, SKT);
  k_up<<<dim3(32, 2, Bsz),256,0,stream>>>(XT, SKT, WEb, WOb, FWSb, B2, H0, GST);
  k_gnfin<<<1,64,0,stream>>>(GST);
  k_gnapply<<<8192,256,0,stream>>>(H0, gn_w, gn_b, pa, GST, HR);
  for (int i=0;i<2;i++){
    k_ln<<<Bsz*Ll/4,256,0,stream>>>(HR, ln_w + i*128, ln_b + i*128, XNB);
    for (int dir=0;dir<2;dir++){
      int br = i*2+dir;
      k_gemm_in<<<dim3(128,4),256,0,stream>>>(XNB, IWB + (size_t)br*512*128, XZB, dir);
      k_conv<<<Bsz*Ll/8,256,0,stream>>>(XZB, conv_w + br*256*4, conv_b + br*256, XI, XIB);
      k_xproj2<<<Bsz*Ll/64,256,0,stream>>>(XIB, WXB + (size_t)br*64*256,
                                           dtproj_w + br*256*8, dtproj_b + br*256, DBL, DTT);
      k_scan1<<<dim3(NC,Bsz),256,0,stream>>>(DTT, DBL, XI, A_log + br*256*16, SP, SQ);
      k_scan2<<<dim3(16,Bsz),256,0,stream>>>(SP, SQ, SH);
      k_scan3<<<dim3(NC,Bsz),256,0,stream>>>(DTT, DBL, XI, A_log + br*256*16, Dp + br*256, SH, XZB, YB);
      k_gemm_out<<<256,256,0,stream>>>(YB, OWB + (size_t)br*128*256, HR, dir);
    }
  }
  k_final<<<dim3(Ll/64,Bsz),256,0,stream>>>(HR, (float*)d_out);
}

// Round 9
// 689.708 us; speedup vs baseline: 11.4902x; 1.2065x over previous
//
#include <hip/hip_runtime.h>
#include <hip/hip_bf16.h>

#define Bsz 4
#define Tt 2048
#define Ll 4096
#define NC 128     // chunks for scan
#define CH 32      // steps per chunk (NC*CH == Ll)

typedef short bf16x8 __attribute__((ext_vector_type(8)));
typedef float f32x4 __attribute__((ext_vector_type(4)));

static __device__ __forceinline__ float bs2f(unsigned short u){
  union{float f; unsigned int i;} v; v.i = ((unsigned int)u)<<16; return v.f;
}
static __device__ __forceinline__ unsigned short f2bs(float f){
  union{float f; unsigned int i;} v; v.f = f;
  unsigned int r = (v.i + 0x7fffu + ((v.i>>16)&1u)) >> 16;
  return (unsigned short)r;
}

// fp32 -> bf16 bulk convert
__global__ void k_cvt(const float* __restrict__ src, unsigned short* __restrict__ dst, int n){
  int i = blockIdx.x*256 + threadIdx.x;
  if (i < n) dst[i] = f2bs(src[i]);
}

// pad xproj_w (4 branches, 40x256) to zero-filled 64x256 bf16
__global__ void k_prepx(const float* __restrict__ xw, unsigned short* __restrict__ wxb){
  int row = blockIdx.x, br = blockIdx.y, col = threadIdx.x;
  float v = (row < 40) ? xw[((size_t)br*40 + row)*256 + col] : 0.f;
  wxb[((size_t)br*64 + row)*256 + col] = f2bs(v);
}

// ---------------------------------------------------------------------------
// Compose upsample-conv weights with fuse matmul; emit bf16 GEMM-ready layouts.
// ---------------------------------------------------------------------------
__global__ void k_compose(const float* __restrict__ up_w, const float* __restrict__ fus_w,
                          const float* __restrict__ fus_b, const float* __restrict__ up_b,
                          unsigned short* __restrict__ WEb, unsigned short* __restrict__ WOb,
                          unsigned short* __restrict__ FWSb, float* __restrict__ BIAS2){
  int i = blockIdx.x;     // 0..255
  int o = threadIdx.x;    // 0..127
  float a0=0.f,a1=0.f,a2=0.f,a3=0.f,a4=0.f;
  for (int c=0;c<256;c++){
    float f = fus_w[o*384+c];
    const float* w = up_w + ((size_t)i*256+c)*5;
    a0 += f*w[0]; a1 += f*w[1]; a2 += f*w[2];
    a3 += f*w[3]; a4 += f*w[4];
  }
  WEb[(size_t)o*768 +       i] = f2bs(a4);
  WEb[(size_t)o*768 + 256 + i] = f2bs(a2);
  WEb[(size_t)o*768 + 512 + i] = f2bs(a0);
  WOb[(size_t)o*512 +       i] = f2bs(a3);
  WOb[(size_t)o*512 + 256 + i] = f2bs(a1);
  if (i<128) FWSb[o*128 + i] = f2bs(fus_w[o*384+256+i]);
  if (i==0){
    float bb = fus_b[o];
    for (int c=0;c<256;c++) bb += fus_w[o*384+c]*up_b[c];
    BIAS2[o]=bb;
  }
}

// transpose x (B,256,T) f32 -> XT (B, T+2, 256) bf16, row t stored at t+1
__global__ __launch_bounds__(256) void k_tx(const float* __restrict__ x, unsigned short* __restrict__ XT){
  __shared__ float tile[64][65];
  int b=blockIdx.z, t0=blockIdx.x*64, i0=blockIdx.y*64;
  int tid=threadIdx.x;
  for (int it=0;it<16;it++){
    int idx=it*256+tid; int ii=idx>>6, tt=idx&63;
    tile[ii][tt] = x[((size_t)b*256+i0+ii)*Tt + t0+tt];
  }
  __syncthreads();
  for (int it=0;it<16;it++){
    int idx=it*256+tid; int tt=idx>>6, ii=idx&63;
    XT[((size_t)b*2050 + t0+tt+1)*256 + i0+ii] = f2bs(tile[ii][tt]);
  }
}

// zero XT halo rows (t=-1 and t=2048)
__global__ void k_zero(unsigned short* __restrict__ XT){
  int tid=threadIdx.x;
  for (int b=0;b<Bsz;b++){
    XT[((size_t)b*2050)*256 + tid] = 0;
    XT[((size_t)b*2050+2049)*256 + tid] = 0;
  }
}

// transpose skip (B,128,L) f32 -> SKT (B,L,128) bf16
__global__ __launch_bounds__(256) void k_ts(const float* __restrict__ skip, unsigned short* __restrict__ SKT){
  __shared__ float tile[64][65];
  int b=blockIdx.z, l0=blockIdx.x*64, s0=blockIdx.y*64;
  int tid=threadIdx.x;
  for (int it=0;it<16;it++){
    int idx=it*256+tid; int ss=idx>>6, ll=idx&63;
    tile[ss][ll] = skip[((size_t)b*128+s0+ss)*Ll + l0+ll];
  }
  __syncthreads();
  for (int it=0;it<16;it++){
    int idx=it*256+tid; int ll=idx>>6, ss=idx&63;
    SKT[((size_t)b*Ll + l0+ll)*128 + s0+ss] = f2bs(tile[ss][ll]);
  }
}

// ---------------------------------------------------------------------------
// MFMA upsample+fuse (see round-4 notes). Block = 64 t x 128 o, one parity.
// ---------------------------------------------------------------------------
__global__ __launch_bounds__(256) void k_up(const unsigned short* __restrict__ XT,
                     const unsigned short* __restrict__ SKT,
                     const unsigned short* __restrict__ WEb, const unsigned short* __restrict__ WOb,
                     const unsigned short* __restrict__ FWSb, const float* __restrict__ B2,
                     float* __restrict__ h0, float* __restrict__ gst){
  __shared__ unsigned short XL[66*264];
  __shared__ unsigned short Wb[128*72];
  __shared__ float red0[256], red1[256];
  int bt = blockIdx.x, par = blockIdx.y, b = blockIdx.z;
  int t0 = bt*64;
  int tid = threadIdx.x;
  int wave = tid>>6, lane = tid&63;
  int wm = wave>>1, wn = wave&1;
  int quad = lane>>4, l16 = lane&15;

  for (int idx=tid; idx<66*32; idx+=256){
    int row = idx>>5, c8 = idx&31;
    *(uint4*)&XL[row*264 + c8*8] = *(const uint4*)&XT[((size_t)b*2050 + t0 + row)*256 + c8*8];
  }

  const unsigned short* Wsrc = par ? WOb : WEb;
  const int Kw = par ? 512 : 768;
  const int tapbase = par ? 1 : 0;
  f32x4 acc[2][4];
  #pragma unroll
  for (int i=0;i<2;i++)
    #pragma unroll
    for (int j=0;j<4;j++) acc[i][j] = (f32x4){0.f,0.f,0.f,0.f};

  int nch = Kw>>6;
  for (int kc=0; kc<nch; kc++){
    __syncthreads();
    #pragma unroll
    for (int it=0; it<4; it++){
      int idx = it*256+tid;
      int row = idx>>3, c8 = idx&7;
      *(uint4*)&Wb[row*72 + c8*8] = *(const uint4*)&Wsrc[(size_t)row*Kw + kc*64 + c8*8];
    }
    __syncthreads();
    #pragma unroll
    for (int ks=0; ks<64; ks+=32){
      int kg = kc*64 + ks;
      int tap = kg>>8, ib = kg&255;
      bf16x8 af[2], bf[4];
      #pragma unroll
      for (int mt=0;mt<2;mt++)
        af[mt] = *(bf16x8*)&XL[(wm*32+mt*16+l16 + tapbase + tap)*264 + ib + quad*8];
      #pragma unroll
      for (int nt=0;nt<4;nt++)
        bf[nt] = *(bf16x8*)&Wb[(wn*64+nt*16+l16)*72 + ks + quad*8];
      #pragma unroll
      for (int mt=0;mt<2;mt++)
        #pragma unroll
        for (int nt=0;nt<4;nt++)
          acc[mt][nt] = __builtin_amdgcn_mfma_f32_16x16x32_bf16(af[mt], bf[nt], acc[mt][nt], 0,0,0);
    }
  }

  __syncthreads();
  for (int idx=tid; idx<64*16; idx+=256){
    int row = idx>>4, c8 = idx&15;
    *(uint4*)&XL[row*136 + c8*8] = *(const uint4*)&SKT[((size_t)b*Ll + 2*(t0+row)+par)*128 + c8*8];
  }
  for (int kc=0; kc<2; kc++){
    __syncthreads();
    #pragma unroll
    for (int it=0; it<4; it++){
      int idx = it*256+tid;
      int row = idx>>3, c8 = idx&7;
      *(uint4*)&Wb[row*72 + c8*8] = *(const uint4*)&FWSb[(size_t)row*128 + kc*64 + c8*8];
    }
    __syncthreads();
    #pragma unroll
    for (int ks=0; ks<64; ks+=32){
      bf16x8 af[2], bf[4];
      #pragma unroll
      for (int mt=0;mt<2;mt++)
        af[mt] = *(bf16x8*)&XL[(wm*32+mt*16+l16)*136 + kc*64 + ks + quad*8];
      #pragma unroll
      for (int nt=0;nt<4;nt++)
        bf[nt] = *(bf16x8*)&Wb[(wn*64+nt*16+l16)*72 + ks + quad*8];
      #pragma unroll
      for (int mt=0;mt<2;mt++)
        #pragma unroll
        for (int nt=0;nt<4;nt++)
          acc[mt][nt] = __builtin_amdgcn_mfma_f32_16x16x32_bf16(af[mt], bf[nt], acc[mt][nt], 0,0,0);
    }
  }

  float s1=0.f, s2=0.f;
  #pragma unroll
  for (int mt=0;mt<2;mt++)
    #pragma unroll
    for (int nt=0;nt<4;nt++)
      #pragma unroll
      for (int r=0;r<4;r++){
        int m = wm*32 + mt*16 + quad*4 + r;
        int lrow = 2*(t0+m) + par;
        int col = wn*64 + nt*16 + l16;
        float v = acc[mt][nt][r] + B2[col];
        h0[((size_t)b*Ll + lrow)*128 + col] = v;
        s1 += v; s2 += v*v;
      }
  red0[tid]=s1; red1[tid]=s2;
  __syncthreads();
  for (int st=128; st>0; st>>=1){
    if (tid<st){ red0[tid]+=red0[tid+st]; red1[tid]+=red1[tid+st]; }
    __syncthreads();
  }
  if (tid==0){ atomicAdd(&gst[b*2], red0[0]); atomicAdd(&gst[b*2+1], red1[0]); }
}

__global__ void k_gnfin(float* gst){
  int b = threadIdx.x;
  if (b < Bsz){
    float n = (float)Ll*128.f;
    float mu = gst[b*2]/n;
    float var = gst[b*2+1]/n - mu*mu;
    gst[8+b]=mu; gst[12+b]=rsqrtf(var+1e-5f);
  }
}

__global__ void k_gnapply(const float* __restrict__ h0, const float* __restrict__ gn_w,
                          const float* __restrict__ gn_b, const float* __restrict__ pa,
                          const float* __restrict__ gst, float* __restrict__ hres){
  size_t idx = (size_t)blockIdx.x*256 + threadIdx.x;
  int c = (int)(idx & 127);
  int b = (int)(idx >> 19);   // L*128 = 2^19
  float mu = gst[8+b], inv = gst[12+b];
  float a = pa[0];
  float v = (h0[idx]-mu)*inv*gn_w[c] + gn_b[c];
  hres[idx] = v>=0.f ? v : a*v;
}

// LayerNorm over 128 ch; 4 rows/block, one wave per row. Writes bf16 XN.
__global__ __launch_bounds__(256) void k_ln(const float* __restrict__ hres, const float* __restrict__ lnw,
                     const float* __restrict__ lnb, unsigned short* __restrict__ xn){
  int row = blockIdx.x*4 + (threadIdx.x>>6);
  int lane = threadIdx.x & 63;
  const float* hp = hres + (size_t)row*128;
  float v0 = hp[lane], v1 = hp[lane+64];
  float s = v0+v1, q = v0*v0+v1*v1;
  #pragma unroll
  for (int off=32; off>0; off>>=1){
    s += __shfl_xor(s, off, 64);
    q += __shfl_xor(q, off, 64);
  }
  float mu = s*(1.f/128.f);
  float rs = rsqrtf(q*(1.f/128.f)-mu*mu + 1e-5f);
  unsigned short* xp = xn + (size_t)row*128;
  xp[lane]    = f2bs((v0-mu)*rs*lnw[lane]    + lnb[lane]);
  xp[lane+64] = f2bs((v1-mu)*rs*lnw[lane+64] + lnb[lane+64]);
}

// ---------------------------------------------------------------------------
// MFMA GEMM in_proj: XZB[row,0:512](bf16) = XN[amap(row),0:128](bf16) @ W^T
// ---------------------------------------------------------------------------
__global__ __launch_bounds__(256) void k_gemm_in(const unsigned short* __restrict__ A,
                          const unsigned short* __restrict__ W,
                          unsigned short* __restrict__ C, int rev){
  __shared__ unsigned short As[128*72];
  __shared__ unsigned short Bs[128*72];
  int tid = threadIdx.x;
  int row0 = blockIdx.x*128;
  int n0   = blockIdx.y*128;
  int wave = tid>>6, lane = tid&63;
  int wm = wave>>1, wn = wave&1;
  int quad = lane>>4, l16 = lane&15;
  f32x4 acc[4][4];
  #pragma unroll
  for (int i=0;i<4;i++)
    #pragma unroll
    for (int j=0;j<4;j++) acc[i][j] = (f32x4){0.f,0.f,0.f,0.f};

  for (int kb=0; kb<128; kb+=64){
    __syncthreads();
    #pragma unroll
    for (int it=0; it<4; it++){
      int idx = it*256 + tid;
      int row = idx>>3, c8 = idx&7;
      int r = row0 + row;
      int p = r & (Ll-1); int bb = r >> 12;
      int src = (bb<<12) + (rev ? (Ll-1-p) : p);
      *(uint4*)&As[row*72 + c8*8] = *(const uint4*)&A[(size_t)src*128 + kb + c8*8];
      *(uint4*)&Bs[row*72 + c8*8] = *(const uint4*)&W[(size_t)(n0+row)*128 + kb + c8*8];
    }
    __syncthreads();
    #pragma unroll
    for (int ks=0; ks<64; ks+=32){
      bf16x8 af[4], bf[4];
      #pragma unroll
      for (int mt=0;mt<4;mt++)
        af[mt] = *(bf16x8*)&As[(wm*64+mt*16+l16)*72 + ks + quad*8];
      #pragma unroll
      for (int nt=0;nt<4;nt++)
        bf[nt] = *(bf16x8*)&Bs[(wn*64+nt*16+l16)*72 + ks + quad*8];
      #pragma unroll
      for (int mt=0;mt<4;mt++)
        #pragma unroll
        for (int nt=0;nt<4;nt++)
          acc[mt][nt] = __builtin_amdgcn_mfma_f32_16x16x32_bf16(af[mt], bf[nt], acc[mt][nt], 0,0,0);
    }
  }
  #pragma unroll
  for (int mt=0;mt<4;mt++)
    #pragma unroll
    for (int nt=0;nt<4;nt++)
      #pragma unroll
      for (int r=0;r<4;r++){
        int row = row0 + wm*64 + mt*16 + quad*4 + r;
        int col = n0 + wn*64 + nt*16 + l16;
        C[(size_t)row*512 + col] = f2bs(acc[mt][nt][r]);
      }
}

// ---------------------------------------------------------------------------
// MFMA GEMM out_proj: HR[amap(row),0:128] += Y[row,0:256](bf16) @ W^T
// ---------------------------------------------------------------------------
__global__ __launch_bounds__(256) void k_gemm_out(const unsigned short* __restrict__ A,
                           const unsigned short* __restrict__ W,
                           float* __restrict__ C, int rev){
  __shared__ unsigned short As[64*72];
  __shared__ unsigned short Bs[128*72];
  int tid = threadIdx.x;
  int row0 = blockIdx.x*64;
  int wave = tid>>6, lane = tid&63;
  int wm = wave>>1, wn = wave&1;
  int quad = lane>>4, l16 = lane&15;
  f32x4 acc[2][4];
  #pragma unroll
  for (int i=0;i<2;i++)
    #pragma unroll
    for (int j=0;j<4;j++) acc[i][j] = (f32x4){0.f,0.f,0.f,0.f};

  for (int kb=0; kb<256; kb+=64){
    __syncthreads();
    #pragma unroll
    for (int it=0; it<2; it++){
      int idx = it*256 + tid;
      int row = idx>>3, c8 = idx&7;
      *(uint4*)&As[row*72 + c8*8] = *(const uint4*)&A[(size_t)(row0+row)*256 + kb + c8*8];
    }
    #pragma unroll
    for (int it=0; it<4; it++){
      int idx = it*256 + tid;
      int row = idx>>3, c8 = idx&7;
      *(uint4*)&Bs[row*72 + c8*8] = *(const uint4*)&W[(size_t)row*256 + kb + c8*8];
    }
    __syncthreads();
    #pragma unroll
    for (int ks=0; ks<64; ks+=32){
      bf16x8 af[2], bf[4];
      #pragma unroll
      for (int mt=0;mt<2;mt++)
        af[mt] = *(bf16x8*)&As[(wm*32+mt*16+l16)*72 + ks + quad*8];
      #pragma unroll
      for (int nt=0;nt<4;nt++)
        bf[nt] = *(bf16x8*)&Bs[(wn*64+nt*16+l16)*72 + ks + quad*8];
      #pragma unroll
      for (int mt=0;mt<2;mt++)
        #pragma unroll
        for (int nt=0;nt<4;nt++)
          acc[mt][nt] = __builtin_amdgcn_mfma_f32_16x16x32_bf16(af[mt], bf[nt], acc[mt][nt], 0,0,0);
    }
  }
  #pragma unroll
  for (int mt=0;mt<2;mt++)
    #pragma unroll
    for (int nt=0;nt<4;nt++)
      #pragma unroll
      for (int r=0;r<4;r++){
        int row = row0 + wm*32 + mt*16 + quad*4 + r;
        int p = row & (Ll-1), bb = row >> 12;
        int dst = (bb<<12) + (rev ? (Ll-1-p) : p);
        int col = wn*64 + nt*16 + l16;
        C[(size_t)dst*128 + col] += acc[mt][nt][r];
      }
}

// Depthwise causal conv (K=4) + bias + SiLU. One thread = 8 d's of one row.
// Writes bf16 xib only (scan reads bf16).
__global__ void k_conv(const unsigned short* __restrict__ xz, const float* __restrict__ cw,
                       const float* __restrict__ cb, unsigned short* __restrict__ xib){
  size_t gid = (size_t)blockIdx.x*256 + threadIdx.x;   // over B*L*32
  int d8 = (int)(gid & 31);
  size_t row = gid >> 5;
  int p = (int)(row & (Ll-1));
  int d0 = d8*8;
  float wv[8][4];
  #pragma unroll
  for (int j=0;j<8;j++){
    float4 w4 = *(const float4*)&cw[(d0+j)*4];
    wv[j][0]=w4.x; wv[j][1]=w4.y; wv[j][2]=w4.z; wv[j][3]=w4.w;
  }
  float acc[8];
  {
    float4 b0 = *(const float4*)&cb[d0];
    float4 b1 = *(const float4*)&cb[d0+4];
    acc[0]=b0.x; acc[1]=b0.y; acc[2]=b0.z; acc[3]=b0.w;
    acc[4]=b1.x; acc[5]=b1.y; acc[6]=b1.z; acc[7]=b1.w;
  }
  #pragma unroll
  for (int k=0;k<4;k++){
    int q = p-3+k;
    if (q>=0){
      uint4 v = *(const uint4*)&xz[((size_t)row-3+k)*512 + d0];
      const unsigned short* s = (const unsigned short*)&v;
      #pragma unroll
      for (int j=0;j<8;j++) acc[j] += wv[j][k]*bs2f(s[j]);
    }
  }
  unsigned short ob[8];
  #pragma unroll
  for (int j=0;j<8;j++){
    float v = acc[j]/(1.f+__expf(-acc[j]));
    ob[j]=f2bs(v);
  }
  *(uint4*)&xib[row*256+d0] = *(uint4*)ob;
}

// ---------------------------------------------------------------------------
// MFMA x_proj + fused dt_proj/softplus.
// ---------------------------------------------------------------------------
__global__ __launch_bounds__(256) void k_xproj2(const unsigned short* __restrict__ xib,
                        const unsigned short* __restrict__ wxb,
                        const float* __restrict__ dtw, const float* __restrict__ dtb,
                        float* __restrict__ dbl, float* __restrict__ dtt){
  __shared__ unsigned short As[64*72];
  __shared__ unsigned short Bs[64*72];
  __shared__ float dblS[64][44];
  int tid = threadIdx.x;
  size_t row0 = (size_t)blockIdx.x*64;
  int wave = tid>>6, lane = tid&63;
  int quad = lane>>4, l16 = lane&15;
  f32x4 acc[4];
  #pragma unroll
  for (int j=0;j<4;j++) acc[j] = (f32x4){0.f,0.f,0.f,0.f};

  for (int kb=0; kb<256; kb+=64){
    __syncthreads();
    #pragma unroll
    for (int it=0; it<2; it++){
      int idx = it*256 + tid;
      int row = idx>>3, c8 = idx&7;
      *(uint4*)&As[row*72 + c8*8] = *(const uint4*)&xib[(row0+row)*256 + kb + c8*8];
      *(uint4*)&Bs[row*72 + c8*8] = *(const uint4*)&wxb[(size_t)row*256 + kb + c8*8];
    }
    __syncthreads();
    #pragma unroll
    for (int ks=0; ks<64; ks+=32){
      bf16x8 af = *(bf16x8*)&As[(wave*16+l16)*72 + ks + quad*8];
      #pragma unroll
      for (int nt=0;nt<4;nt++){
        bf16x8 bf = *(bf16x8*)&Bs[(nt*16+l16)*72 + ks + quad*8];
        acc[nt] = __builtin_amdgcn_mfma_f32_16x16x32_bf16(af, bf, acc[nt], 0,0,0);
      }
    }
  }
  #pragma unroll
  for (int nt=0;nt<4;nt++)
    #pragma unroll
    for (int r=0;r<4;r++){
      int m = wave*16 + quad*4 + r;
      int col = nt*16 + l16;
      if (col < 40){
        float v = acc[nt][r];
        dbl[(row0+m)*40 + col] = v;
        dblS[m][col] = v;
      }
    }
  __syncthreads();
  // phase B: thread = d (0..255)
  float wv[8];
  {
    float4 w0 = *(const float4*)&dtw[tid*8];
    float4 w1 = *(const float4*)&dtw[tid*8+4];
    wv[0]=w0.x; wv[1]=w0.y; wv[2]=w0.z; wv[3]=w0.w;
    wv[4]=w1.x; wv[5]=w1.y; wv[6]=w1.z; wv[7]=w1.w;
  }
  float bb = dtb[tid];
  for (int rr=0; rr<64; rr++){
    float a = bb;
    #pragma unroll
    for (int r=0;r<8;r++) a += dblS[rr][r]*wv[r];
    float v = (a>20.f)? a : log1pf(__expf(a));
    dtt[(row0+rr)*256 + tid] = v;
  }
}

// ---------------------------------------------------------------------------
// Chunked scan, one thread per d, n-state in registers. xi read as bf16.
// ---------------------------------------------------------------------------
__global__ __launch_bounds__(256) void k_scan1(const float* __restrict__ dt, const float* __restrict__ dbl,
                       const unsigned short* __restrict__ xib, const float* __restrict__ Alog,
                       float* __restrict__ P, float* __restrict__ Q){
  __shared__ float BcS[CH][16];
  int b = blockIdx.y, c = blockIdx.x;
  int d = threadIdx.x;
  size_t base = (size_t)b*Ll + (size_t)c*CH;
  for (int idx=d; idx<CH*16; idx+=256){
    int p = idx>>4, n = idx&15;
    BcS[p][n] = dbl[(base+p)*40 + 8 + n];
  }
  float A[16];
  #pragma unroll
  for (int j=0;j<4;j++){
    float4 a4 = *(const float4*)&Alog[d*16 + j*4];
    A[4*j]=-__expf(a4.x); A[4*j+1]=-__expf(a4.y); A[4*j+2]=-__expf(a4.z); A[4*j+3]=-__expf(a4.w);
  }
  __syncthreads();
  float h[16], pr[16];
  #pragma unroll
  for (int n=0;n<16;n++){ h[n]=0.f; pr[n]=1.f; }
  const float* dtp = dt + base*256 + d;
  const unsigned short* xip = xib + base*256 + d;
  for (int p=0;p<CH;p++){
    float dtv = dtp[(size_t)p*256];
    float xiv = bs2f(xip[(size_t)p*256]);
    float dx = dtv*xiv;
    #pragma unroll
    for (int n=0;n<16;n++){
      float a = __expf(dtv*A[n]);
      h[n] = a*h[n] + BcS[p][n]*dx;
      pr[n] *= a;
    }
  }
  size_t sbase = ((size_t)(b*NC + c))*4096 + d*16;
  #pragma unroll
  for (int j=0;j<4;j++){
    *(float4*)&P[sbase + 4*j] = (float4){pr[4*j],pr[4*j+1],pr[4*j+2],pr[4*j+3]};
    *(float4*)&Q[sbase + 4*j] = (float4){h[4*j],h[4*j+1],h[4*j+2],h[4*j+3]};
  }
}

__global__ __launch_bounds__(256) void k_scan2(const float* __restrict__ P, const float* __restrict__ Q,
                       float* __restrict__ Hs){
  int b = blockIdx.y;
  int dn = blockIdx.x*256 + threadIdx.x;   // 0..4095
  float H = 0.f;
  for (int c=0;c<NC;c++){
    size_t idx = ((size_t)(b*NC + c))*4096 + dn;
    Hs[idx] = H;
    H = P[idx]*H + Q[idx];
  }
}

__global__ __launch_bounds__(256) void k_scan3(const float* __restrict__ dt, const float* __restrict__ dbl,
                       const unsigned short* __restrict__ xib, const float* __restrict__ Alog,
                       const float* __restrict__ Dpw, const float* __restrict__ Hs,
                       const unsigned short* __restrict__ xz, unsigned short* __restrict__ y){
  __shared__ float BcS[CH][16];
  __shared__ float CcS[CH][16];
  int b = blockIdx.y, c = blockIdx.x;
  int d = threadIdx.x;
  size_t base = (size_t)b*Ll + (size_t)c*CH;
  for (int idx=d; idx<CH*16; idx+=256){
    int p = idx>>4, n = idx&15;
    BcS[p][n] = dbl[(base+p)*40 + 8 + n];
    CcS[p][n] = dbl[(base+p)*40 + 24 + n];
  }
  float A[16];
  #pragma unroll
  for (int j=0;j<4;j++){
    float4 a4 = *(const float4*)&Alog[d*16 + j*4];
    A[4*j]=-__expf(a4.x); A[4*j+1]=-__expf(a4.y); A[4*j+2]=-__expf(a4.z); A[4*j+3]=-__expf(a4.w);
  }
  float Dp = Dpw[d];
  float h[16];
  size_t sbase = ((size_t)(b*NC + c))*4096 + d*16;
  #pragma unroll
  for (int j=0;j<4;j++){
    float4 h4 = *(const float4*)&Hs[sbase + 4*j];
    h[4*j]=h4.x; h[4*j+1]=h4.y; h[4*j+2]=h4.z; h[4*j+3]=h4.w;
  }
  __syncthreads();
  const float* dtp = dt + base*256 + d;
  const unsigned short* xip = xib + base*256 + d;
  const unsigned short* zp = xz + base*512 + 256 + d;
  unsigned short* yp = y + base*256 + d;
  for (int p=0;p<CH;p++){
    float dtv = dtp[(size_t)p*256];
    float xiv = bs2f(xip[(size_t)p*256]);
    float dx = dtv*xiv;
    float acc = 0.f;
    #pragma unroll
    for (int n=0;n<16;n++){
      float a = __expf(dtv*A[n]);
      h[n] = a*h[n] + BcS[p][n]*dx;
      acc += h[n]*CcS[p][n];
    }
    float z = bs2f(zp[(size_t)p*512]);
    float g = z/(1.f+__expf(-z));
    yp[(size_t)p*256] = f2bs((acc + Dp*xiv)*g);
  }
}

// final transpose (B,L,128) fp32 -> (B,128,L) fp32
__global__ __launch_bounds__(256) void k_final(const float* __restrict__ hres, float* __restrict__ out){
  __shared__ float tile[64*129];
  int b = blockIdx.y, l0 = blockIdx.x*64;
  int tid = threadIdx.x;
  for (int q=0;q<32;q++){
    int idx = q*256 + tid;
    int l = idx >> 7, c = idx & 127;
    tile[l*129 + c] = hres[((size_t)b*Ll + l0 + l)*128 + c];
  }
  __syncthreads();
  int lo = tid & 63; int cbase = tid >> 6;
  for (int q=0;q<32;q++){
    int c = cbase + q*4;
    out[((size_t)b*128 + c)*Ll + l0 + lo] = tile[lo*129 + c];
  }
}

extern "C" void kernel_launch(void* const* d_in, const int* in_sizes, int n_in,
                              void* d_out, int out_size, void* d_ws, size_t ws_size,
                              hipStream_t stream){
  const float* x      = (const float*)d_in[0];
  const float* skip   = (const float*)d_in[1];
  const float* up_w   = (const float*)d_in[2];
  const float* up_b   = (const float*)d_in[3];
  const float* fus_w  = (const float*)d_in[4];
  const float* fus_b  = (const float*)d_in[5];
  const float* gn_w   = (const float*)d_in[6];
  const float* gn_b   = (const float*)d_in[7];
  const float* pa     = (const float*)d_in[8];
  const float* ln_w   = (const float*)d_in[9];
  const float* ln_b   = (const float*)d_in[10];
  const float* in_w   = (const float*)d_in[11];
  const float* conv_w = (const float*)d_in[12];
  const float* conv_b = (const float*)d_in[13];
  const float* xproj_w= (const float*)d_in[14];
  const float* dtproj_w=(const float*)d_in[15];
  const float* dtproj_b=(const float*)d_in[16];
  const float* A_log  = (const float*)d_in[17];
  const float* Dp     = (const float*)d_in[18];
  const float* out_w  = (const float*)d_in[19];

  // Workspace layout (~100 MiB budget; round-7 post-mortem: 108 MB corrupted
  // harness memory, 99.85 MB fine). Current total ~88 MB.
  //   U1: XT+SKT (preamble only) / SP,SQ,SH (mamba loop only; NC=128)
  //   U2: H0 (preamble only)     / XIB (mamba loop only)
  float* w = (float*)d_ws;
  size_t off=0;
  float* B2 = w+off; off += 128;
  float* GST= w+off; off += 16;
  off = (off+3)&~(size_t)3;
  float* HR = w+off; off += (size_t)Bsz*Ll*128;
  float* DBL= w+off; off += (size_t)Bsz*Ll*40;
  float* DTT= w+off; off += (size_t)Bsz*Ll*256;
  unsigned short* XNB = (unsigned short*)(w+off); off += (size_t)Bsz*Ll*128/2;
  unsigned short* XZB = (unsigned short*)(w+off); off += (size_t)Bsz*Ll*512/2;
  unsigned short* YB  = (unsigned short*)(w+off); off += (size_t)Bsz*Ll*256/2;
  unsigned short* IWB = (unsigned short*)(w+off); off += 2*2*512*128/2;
  unsigned short* OWB = (unsigned short*)(w+off); off += 2*2*128*256/2;
  unsigned short* WXB = (unsigned short*)(w+off); off += 2*2*64*256/2;
  unsigned short* WEb = (unsigned short*)(w+off); off += 768*128/2;
  unsigned short* WOb = (unsigned short*)(w+off); off += 512*128/2;
  unsigned short* FWSb= (unsigned short*)(w+off); off += 128*128/2;
  // U1: max(XT 1,049,604 + SKT 1,048,576, SP+SQ+SH = 3*Bsz*NC*4096) floats
  size_t scanbuf = (size_t)Bsz*NC*4096;   // 2,097,152 @ NC=128
  float* U1 = w+off; off += 3*scanbuf;
  unsigned short* XT  = (unsigned short*)U1;
  unsigned short* SKT = (unsigned short*)(U1 + 1049604);
  float* SP = U1;
  float* SQ = U1 + scanbuf;
  float* SH = U1 + 2*scanbuf;
  // U2: max(H0, XIB) = 2,097,152 floats
  float* U2 = w+off; off += (size_t)Bsz*Ll*128;
  float* H0 = U2;
  unsigned short* XIB = (unsigned short*)U2;

  hipMemsetAsync(GST, 0, 16*sizeof(float), stream);
  k_cvt<<<(2*2*512*128+255)/256,256,0,stream>>>(in_w, IWB, 2*2*512*128);
  k_cvt<<<(2*2*128*256+255)/256,256,0,stream>>>(out_w, OWB, 2*2*128*256);
  k_prepx<<<dim3(64,4),256,0,stream>>>(xproj_w, WXB);
  k_compose<<<256,128,0,stream>>>(up_w, fus_w, fus_b, up_b, WEb, WOb, FWSb, B2);
  k_tx<<<dim3(Tt/64, 4, Bsz),256,0,stream>>>(x, XT);
  k_zero<<<1,256,0,stream>>>(XT);
  k_ts<<<dim3(Ll/64, 2, Bsz),256,0,stream>>>(skip, SKT);
  k_up<<<dim3(32, 2, Bsz),256,0,stream>>>(XT, SKT, WEb, WOb, FWSb, B2, H0, GST);
  k_gnfin<<<1,64,0,stream>>>(GST);
  k_gnapply<<<8192,256,0,stream>>>(H0, gn_w, gn_b, pa, GST, HR);
  for (int i=0;i<2;i++){
    k_ln<<<Bsz*Ll/4,256,0,stream>>>(HR, ln_w + i*128, ln_b + i*128, XNB);
    for (int dir=0;dir<2;dir++){
      int br = i*2+dir;
      k_gemm_in<<<dim3(128,4),256,0,stream>>>(XNB, IWB + (size_t)br*512*128, XZB, dir);
      k_conv<<<Bsz*Ll/8,256,0,stream>>>(XZB, conv_w + br*256*4, conv_b + br*256, XIB);
      k_xproj2<<<Bsz*Ll/64,256,0,stream>>>(XIB, WXB + (size_t)br*64*256,
                                           dtproj_w + br*256*8, dtproj_b + br*256, DBL, DTT);
      k_scan1<<<dim3(NC,Bsz),256,0,stream>>>(DTT, DBL, XIB, A_log + br*256*16, SP, SQ);
      k_scan2<<<dim3(16,Bsz),256,0,stream>>>(SP, SQ, SH);
      k_scan3<<<dim3(NC,Bsz),256,0,stream>>>(DTT, DBL, XIB, A_log + br*256*16, Dp + br*256, SH, XZB, YB);
      k_gemm_out<<<256,256,0,stream>>>(YB, OWB + (size_t)br*128*256, HR, dir);
    }
  }
  k_final<<<dim3(Ll/64,Bsz),256,0,stream>>>(HR, (float*)d_out);
}